// Round 9
// baseline (1655.832 us; speedup 1.0000x reference)
//
#include <hip/hip_runtime.h>
#include <math.h>

#define N_PTS 6000
#define DIM   1024
#define KSEL  300
#define GG    16
#define DGR   64
#define WSTR  6016   // padded row stride for logits W (6000 -> 6016)
#define XSTR  3072   // X = [hi|mid|lo] bf16 split, row stride

typedef short bf16x8 __attribute__((ext_vector_type(8)));
typedef float floatx4 __attribute__((ext_vector_type(4)));

__device__ __forceinline__ unsigned short f2bf(float x) {
    unsigned u = __float_as_uint(x);
    unsigned r = u + 0x7FFFu + ((u >> 16) & 1u);   // RNE
    return (unsigned short)(r >> 16);
}
__device__ __forceinline__ float bf2f(unsigned short h) {
    return __uint_as_float(((unsigned)h) << 16);
}

__device__ __forceinline__ void async_copy16(const void* gsrc, void* ldst) {
    __builtin_amdgcn_global_load_lds(
        (const __attribute__((address_space(1))) void*)gsrc,
        (__attribute__((address_space(3))) void*)ldst,
        16, 0, 0);
}

// ---------------------------------------------------------------------------
// MFMA bf16 GEMM, NT: C[i][j] = scale * sum_k A[i,k]*B[j,k] (+bias[j])
// 128x128 tile, BK=32, 256 threads (4 waves, each 64x64 = 4x4 16x16 tiles).
// GRAM: A=B=X=[hi|mid|lo] (lda 3072); 6 chunk passes, compile-time offsets;
//       triangular grid (bi<=bj), 1/cdist epilogue. Epilogue stages each
//       64-row half-tile in LDS (epi[64][129]) then writes BOTH the direct
//       and the mirrored tile with full-line coalesced float4 stores —
//       R7's FETCH=693MB was ~576MB RFO from 16B-granular mirror writes.
// OBF16: store output as bf16 (for q, kk feeding the aff MFMA).
// ---------------------------------------------------------------------------
template<bool GRAM, bool OBF16>
__global__ __launch_bounds__(256)
void mfma_gemm(const void* Av, long lda, long az,
               const void* Bv, long ldb, long bz,
               void* Cv, long ldc, long cz,
               int M, int N, int Kd,
               const float* __restrict__ bias, long biasz,
               float scale, const float* __restrict__ sqn, int nbm)
{
    __shared__ unsigned short As[128 * 32];
    __shared__ unsigned short Bs[128 * 32];
    const int t = threadIdx.x;
    const int w = t >> 6, l = t & 63;
    const int wr = w >> 1, wc = w & 1;

    int row0, col0, bi = 0, bj = 0;
    if (GRAM) {
        int tt = blockIdx.x, rem = nbm;
        while (tt >= rem) { tt -= rem; bi++; rem--; }
        bj = bi + tt;
        row0 = bi * 128; col0 = bj * 128;
    } else {
        row0 = blockIdx.y * 128; col0 = blockIdx.x * 128;
    }
    const int z = blockIdx.z;
    const unsigned short* Ab = (const unsigned short*)Av + (long)z * az;
    const unsigned short* Bb = (const unsigned short*)Bv + (long)z * bz;

    floatx4 acc[4][4];
#pragma unroll
    for (int i = 0; i < 4; i++)
#pragma unroll
        for (int j = 0; j < 4; j++) acc[i][j] = (floatx4){0.f, 0.f, 0.f, 0.f};

    // clamped staging row indices (hoisted out of the K loop)
    int ra0 = row0 + (w * 2 + 0) * 16 + (l >> 2); ra0 = ra0 < M ? ra0 : M - 1;
    int ra1 = row0 + (w * 2 + 1) * 16 + (l >> 2); ra1 = ra1 < M ? ra1 : M - 1;
    int rb0 = col0 + (w * 2 + 0) * 16 + (l >> 2); rb0 = rb0 < N ? rb0 : N - 1;
    int rb1 = col0 + (w * 2 + 1) * 16 + (l >> 2); rb1 = rb1 < N ? rb1 : N - 1;
    const long lane_off = (l & 3) * 8;
    const unsigned short* gA0 = Ab + (long)ra0 * lda + lane_off;
    const unsigned short* gA1 = Ab + (long)ra1 * lda + lane_off;
    const unsigned short* gB0 = Bb + (long)rb0 * ldb + lane_off;
    const unsigned short* gB1 = Bb + (long)rb1 * ldb + lane_off;
    unsigned short* lA0 = As + ((w * 2 + 0) * 16) * 32;
    unsigned short* lA1 = As + ((w * 2 + 1) * 16) * 32;
    unsigned short* lB0 = Bs + ((w * 2 + 0) * 16) * 32;
    unsigned short* lB1 = Bs + ((w * 2 + 1) * 16) * 32;

    auto kstep = [&](long offA, long offB) {
        async_copy16(gA0 + offA, (void*)lA0);
        async_copy16(gA1 + offA, (void*)lA1);
        async_copy16(gB0 + offB, (void*)lB0);
        async_copy16(gB1 + offB, (void*)lB1);
        __syncthreads();
        bf16x8 af[4], bfr[4];
#pragma unroll
        for (int ti = 0; ti < 4; ti++)
            af[ti] = *(const bf16x8*)(As + (wr * 64 + ti * 16 + (l & 15)) * 32 + (l >> 4) * 8);
#pragma unroll
        for (int tj = 0; tj < 4; tj++)
            bfr[tj] = *(const bf16x8*)(Bs + (wc * 64 + tj * 16 + (l & 15)) * 32 + (l >> 4) * 8);
#pragma unroll
        for (int ti = 0; ti < 4; ti++)
#pragma unroll
            for (int tj = 0; tj < 4; tj++)
                acc[ti][tj] = __builtin_amdgcn_mfma_f32_16x16x32_bf16(
                    af[ti], bfr[tj], acc[ti][tj], 0, 0, 0);
        __syncthreads();
    };

    if (GRAM) {
        // 6 chunk passes, compile-time part offsets (hi=0, mid=1024, lo=2048)
#pragma unroll 1
        for (int k0 = 0; k0 < 1024; k0 += 32) kstep(k0, k0);              // hi.hi
#pragma unroll 1
        for (int k0 = 0; k0 < 1024; k0 += 32) kstep(k0, k0 + 1024);      // hi.mid
#pragma unroll 1
        for (int k0 = 0; k0 < 1024; k0 += 32) kstep(k0 + 1024, k0);      // mid.hi
#pragma unroll 1
        for (int k0 = 0; k0 < 1024; k0 += 32) kstep(k0 + 1024, k0 + 1024); // mid.mid
#pragma unroll 1
        for (int k0 = 0; k0 < 1024; k0 += 32) kstep(k0, k0 + 2048);      // hi.lo
#pragma unroll 1
        for (int k0 = 0; k0 < 1024; k0 += 32) kstep(k0 + 2048, k0);      // lo.hi
    } else {
#pragma unroll 1
        for (int k0 = 0; k0 < Kd; k0 += 32) kstep(k0, k0);
    }

    float* Cf = (float*)Cv + (long)z * cz;

    if constexpr (GRAM) {
        // LDS-transpose epilogue: two 64-row halves, fully coalesced stores.
        __shared__ float epi[64][129];   // odd stride: column reads 2-way (free)
#pragma unroll 1
        for (int half = 0; half < 2; half++) {
            if (wr == half) {
#pragma unroll
                for (int ti = 0; ti < 4; ti++) {
#pragma unroll
                    for (int tj = 0; tj < 4; tj++) {
                        const int lc = wc * 64 + tj * 16 + (l & 15);
                        const int lr = ti * 16 + (l >> 4) * 4;
                        const int c = col0 + lc;
                        const int cc = c < N ? c : N - 1;
#pragma unroll
                        for (int reg = 0; reg < 4; reg++) {
                            const int r = row0 + half * 64 + lr + reg;
                            float val;
                            if (r == c) val = INFINITY;
                            else {
                                const int rc = r < M ? r : M - 1;
                                float sq = sqn[rc] + sqn[cc] - 2.f * acc[ti][tj][reg];
                                val = 1.0f / sqrtf(fmaxf(sq, 0.f));
                            }
                            epi[lr + reg][lc] = val;
                        }
                    }
                }
            }
            __syncthreads();
            {   // direct: C[r][col0..col0+128), float4 rows (full 128B lines)
                const int lr = t >> 2;
                const int c0l = (t & 3) * 32;
                const int rg = row0 + half * 64 + lr;
                if (rg < M) {
#pragma unroll
                    for (int q4 = 0; q4 < 8; q4++) {
                        const int cl = c0l + q4 * 4;
                        const int cg = col0 + cl;
                        if (cg < N) {
                            float4 v = make_float4(epi[lr][cl], epi[lr][cl + 1],
                                                   epi[lr][cl + 2], epi[lr][cl + 3]);
                            *(float4*)(Cf + (long)rg * ldc + cg) = v;
                        }
                    }
                }
            }
            if (bi != bj) {  // mirror: C[c][row-half], float4 along r (256B segs)
                const int lc = t >> 1;
                const int r0l = (t & 1) * 32;
                const int cg = col0 + lc;
                if (cg < N) {
#pragma unroll
                    for (int q4 = 0; q4 < 8; q4++) {
                        const int rl = r0l + q4 * 4;
                        const int rg = row0 + half * 64 + rl;
                        if (rg < M) {
                            float4 v = make_float4(epi[rl][lc], epi[rl + 1][lc],
                                                   epi[rl + 2][lc], epi[rl + 3][lc]);
                            *(float4*)(Cf + (long)cg * ldc + rg) = v;
                        }
                    }
                }
            }
            __syncthreads();
        }
        return;
    }

    unsigned short* Cb = (unsigned short*)Cv + (long)z * cz;
    const float* bias_p = bias ? bias + (long)z * biasz : nullptr;
#pragma unroll
    for (int ti = 0; ti < 4; ti++) {
#pragma unroll
        for (int tj = 0; tj < 4; tj++) {
            const int c = col0 + wc * 64 + tj * 16 + (l & 15);
            const int rb = row0 + wr * 64 + ti * 16 + (l >> 4) * 4;
#pragma unroll
            for (int reg = 0; reg < 4; reg++) {
                int r = rb + reg;
                if (r >= M || c >= N) continue;
                float v = acc[ti][tj][reg] * scale;
                if (bias_p) v += bias_p[c];
                if (OBF16) Cb[(long)r * ldc + c] = f2bf(v);
                else       Cf[(long)r * ldc + c] = v;
            }
        }
    }
}

// ---------------------------------------------------------------------------
// fp32 SGEMM kept for the small Wv projection only.
// ---------------------------------------------------------------------------
#define BM 128
#define BN 128
#define BKK 8
#define TM 8
#define TN 8

template<bool TRANSB>
__global__ __launch_bounds__(256)
void sgemm_kernel(const float* __restrict__ A, long lda, long az,
                  const float* __restrict__ B, long ldb, long bz,
                  float* __restrict__ C, long ldc, long cz,
                  int M, int N, int Kd,
                  const float* __restrict__ bias, long biasz, float scale)
{
    __shared__ float As[BKK][BM];
    __shared__ float Bs[BKK][BN];
    const int t = threadIdx.x;
    const int z = blockIdx.z;
    A += (long)z * az; B += (long)z * bz; C += (long)z * cz;
    const float* bias_p = bias ? (bias + (long)z * biasz) : nullptr;
    const int row0 = blockIdx.y * BM;
    const int col0 = blockIdx.x * BN;
    const int tx = t & 15, ty = t >> 4;

    float acc[TM][TN];
#pragma unroll
    for (int i = 0; i < TM; i++)
#pragma unroll
        for (int j = 0; j < TN; j++) acc[i][j] = 0.f;

    const int lrow = t >> 1;
    const int lcol = (t & 1) * 4;

    for (int k0 = 0; k0 < Kd; k0 += BKK) {
        {
            int r = row0 + lrow; r = (r < M) ? r : (M - 1);
            float4 v = *(const float4*)(A + (long)r * lda + (k0 + lcol));
            As[lcol + 0][lrow] = v.x; As[lcol + 1][lrow] = v.y;
            As[lcol + 2][lrow] = v.z; As[lcol + 3][lrow] = v.w;
        }
        {
            int r = col0 + lrow; r = (r < N) ? r : (N - 1);
            float4 v = *(const float4*)(B + (long)r * ldb + (k0 + lcol));
            Bs[lcol + 0][lrow] = v.x; Bs[lcol + 1][lrow] = v.y;
            Bs[lcol + 2][lrow] = v.z; Bs[lcol + 3][lrow] = v.w;
        }
        __syncthreads();
#pragma unroll
        for (int kk = 0; kk < BKK; kk++) {
            float a[TM], b[TN];
#pragma unroll
            for (int i = 0; i < TM; i++) a[i] = As[kk][ty * TM + i];
#pragma unroll
            for (int j = 0; j < TN; j++) b[j] = Bs[kk][tx * TN + j];
#pragma unroll
            for (int i = 0; i < TM; i++)
#pragma unroll
                for (int j = 0; j < TN; j++)
                    acc[i][j] = fmaf(a[i], b[j], acc[i][j]);
        }
        __syncthreads();
    }
#pragma unroll
    for (int i = 0; i < TM; i++) {
        int r = row0 + ty * TM + i;
        if (r >= M) continue;
#pragma unroll
        for (int j = 0; j < TN; j++) {
            int c = col0 + tx * TN + j;
            if (c >= N) continue;
            float v = acc[i][j] * scale;
            if (bias_p) v += bias_p[c];
            C[(long)r * ldc + c] = v;
        }
    }
}

// ---------------------------------------------------------------------------
// Fused: sqn[r] = ||feat[r]||^2  AND  X = [hi|mid|lo] bf16 3-way split.
// ---------------------------------------------------------------------------
__global__ __launch_bounds__(256)
void sqnpack3_kernel(const float* __restrict__ feat,
                     unsigned short* __restrict__ X, float* __restrict__ sqn)
{
    const int r = blockIdx.x, t = threadIdx.x;
    float4 v = *(const float4*)(feat + (long)r * DIM + t * 4);
    float s = v.x * v.x + v.y * v.y + v.z * v.z + v.w * v.w;

    ushort4 hi, mid, lo;
    float rx, ry, rz, rw;
    hi.x = f2bf(v.x); rx = v.x - bf2f(hi.x);
    hi.y = f2bf(v.y); ry = v.y - bf2f(hi.y);
    hi.z = f2bf(v.z); rz = v.z - bf2f(hi.z);
    hi.w = f2bf(v.w); rw = v.w - bf2f(hi.w);
    mid.x = f2bf(rx); rx -= bf2f(mid.x);
    mid.y = f2bf(ry); ry -= bf2f(mid.y);
    mid.z = f2bf(rz); rz -= bf2f(mid.z);
    mid.w = f2bf(rw); rw -= bf2f(mid.w);
    lo.x = f2bf(rx); lo.y = f2bf(ry); lo.z = f2bf(rz); lo.w = f2bf(rw);
    *(ushort4*)(X + (long)r * XSTR + t * 4) = hi;
    *(ushort4*)(X + (long)r * XSTR + 1024 + t * 4) = mid;
    *(ushort4*)(X + (long)r * XSTR + 2048 + t * 4) = lo;

#pragma unroll
    for (int o = 32; o > 0; o >>= 1) s += __shfl_down(s, o);
    __shared__ float sr[4];
    if ((t & 63) == 0) sr[t >> 6] = s;
    __syncthreads();
    if (t == 0) sqn[r] = sr[0] + sr[1] + sr[2] + sr[3];
}

// Both weight conversions in one launch: blocks [0,1024) -> Wq, [1024,2048) -> Wk
__global__ __launch_bounds__(256)
void wconv2_kernel(const float* __restrict__ Wq, const float* __restrict__ Wk,
                   unsigned short* __restrict__ Wq_b, unsigned short* __restrict__ Wk_b)
{
    const int b = blockIdx.x;
    const float* src = (b < 1024) ? Wq : Wk;
    unsigned short* dst = (b < 1024) ? Wq_b : Wk_b;
    const long i = ((long)(b & 1023) * 256 + threadIdx.x) * 4;
    float4 v = *(const float4*)(src + i);
    ushort4 o;
    o.x = f2bf(v.x); o.y = f2bf(v.y); o.z = f2bf(v.z); o.w = f2bf(v.w);
    *(ushort4*)(dst + i) = o;
}

// featT[d][r] = bf16(feat[r][d]), 1024 x 6016 (cols 6000..6015 zero)
__global__ __launch_bounds__(256)
void transpose_kernel(const float* __restrict__ feat, unsigned short* __restrict__ featT)
{
    __shared__ unsigned short tile[32][33];
    const int bx = blockIdx.x;   // d-block 0..31
    const int by = blockIdx.y;   // r-block 0..187
    const int t = threadIdx.x;
    const int lr = t >> 3;
    const int lc = (t & 7) * 4;
    const int r = by * 32 + lr;
    if (r < N_PTS) {
        float4 v = *(const float4*)(feat + (long)r * DIM + bx * 32 + lc);
        tile[lr][lc + 0] = f2bf(v.x); tile[lr][lc + 1] = f2bf(v.y);
        tile[lr][lc + 2] = f2bf(v.z); tile[lr][lc + 3] = f2bf(v.w);
    } else {
        tile[lr][lc + 0] = 0; tile[lr][lc + 1] = 0;
        tile[lr][lc + 2] = 0; tile[lr][lc + 3] = 0;
    }
    __syncthreads();
    const int orow = bx * 32 + lr;
    ushort4 o;
    o.x = tile[lc + 0][lr]; o.y = tile[lc + 1][lr];
    o.z = tile[lc + 2][lr]; o.w = tile[lc + 3][lr];
    *(ushort4*)(featT + (long)orow * WSTR + by * 32 + lc) = o;
}

// ---------------------------------------------------------------------------
// Greedy FPS — R4 reduction, float4 load path (R7, measured-good).
// ---------------------------------------------------------------------------
#define FPS_T 1024

__global__ __launch_bounds__(1024)
void fps_kernel(const float* __restrict__ Drec, int* __restrict__ idxout)
{
    const int t = threadIdx.x;
    const bool act = t < 750;
    float ds[8];
    if (act) {
        const float4* p = (const float4*)Drec + 2 * t;
        float4 a0 = p[0], a1 = p[1];
        ds[0] = a0.x; ds[1] = a0.y; ds[2] = a0.z; ds[3] = a0.w;
        ds[4] = a1.x; ds[5] = a1.y; ds[6] = a1.z; ds[7] = a1.w;
    } else {
#pragma unroll
        for (int j = 0; j < 8; j++) ds[j] = INFINITY;
    }
    __shared__ unsigned long long red[16];
    __shared__ int s_sel;
    if (t == 0) idxout[0] = 0;

    for (int it = 1; it < KSEL; it++) {
        float mv = ds[0]; int mi = 8 * t;
#pragma unroll
        for (int j = 1; j < 8; j++) {
            if (ds[j] < mv) { mv = ds[j]; mi = 8 * t + j; }
        }
        unsigned long long key = act
            ? (((unsigned long long)__float_as_uint(mv) << 32) | (unsigned)mi)
            : ~0ull;
#pragma unroll
        for (int o = 32; o > 0; o >>= 1) {
            unsigned long long other = __shfl_down(key, o);
            if (other < key) key = other;
        }
        if ((t & 63) == 0) red[t >> 6] = key;
        __syncthreads();
        if (t < 64) {
            unsigned long long k2 = (t < 16) ? red[t] : ~0ull;
#pragma unroll
            for (int o = 8; o > 0; o >>= 1) {
                unsigned long long other = __shfl_down(k2, o);
                if (other < k2) k2 = other;
            }
            if (t == 0) s_sel = (int)(unsigned)(k2 & 0xffffffffull);
        }
        __syncthreads();
        const int sel = s_sel;
        if (t == 0) idxout[it] = sel;
        if (act) {
            const float4* rp = (const float4*)(Drec + (long)sel * N_PTS) + 2 * t;
            float4 r0 = rp[0], r1 = rp[1];
            ds[0] += r0.x; ds[1] += r0.y; ds[2] += r0.z; ds[3] += r0.w;
            ds[4] += r1.x; ds[5] += r1.y; ds[6] += r1.z; ds[7] += r1.w;
        }
    }
}

__global__ __launch_bounds__(256)
void gatherb_kernel(const unsigned short* __restrict__ X, const int* __restrict__ idx,
                    unsigned short* __restrict__ roi)
{
    const int k = blockIdx.x, t = threadIdx.x;
    const unsigned short* src = X + (long)idx[k] * XSTR;
    *(ushort4*)(roi + (long)k * DIM + t * 4) = *(const ushort4*)(src + t * 4);
}

// ---------------------------------------------------------------------------
// Fused gate + softmax: one block per (k,g) row of W (in-place fp32 -> bf16).
// ---------------------------------------------------------------------------
__global__ __launch_bounds__(256)
void gatesoftmax_kernel(const float* __restrict__ bboxes,
                        const int* __restrict__ idx,
                        const float* __restrict__ Wg,
                        const float* __restrict__ bgp,
                        float* __restrict__ W)
{
    __shared__ float lg[WSTR];      // 24 KB: logits, then exp values
    __shared__ float swg[64];
    __shared__ float sred[4];
    __shared__ float sbb[4];
    __shared__ float sMS;
    const int t = threadIdx.x;
    const int row = blockIdx.x;     // k*GG + g
    const int k = row >> 4, g = row & 15;
    float* rowp = W + (long)row * WSTR;

    if (t < 64) swg[t] = Wg[g * 64 + t];
    if (t < 4)  sbb[t] = bboxes[(long)idx[k] * 4 + t];
    __syncthreads();

    const float x1 = sbb[0], y1 = sbb[1], x2 = sbb[2], y2 = sbb[3];
    const float w  = x2 - x1 + 1.f, h = y2 - y1 + 1.f;
    const float cx = 0.5f * (x1 + x2), cy = 0.5f * (y1 + y2);
    const float bg_g = bgp[g];
    const float rdm[8] = { 100.0f, 42.169650342858226f, 17.782794100389228f,
                           7.498942093324559f, 3.1622776601683795f,
                           1.333521432163324f, 0.5623413251903491f,
                           0.23713737056616552f };

    float m = -INFINITY;
    for (int n = t; n < N_PTS; n += 256) {
        const float aff = rowp[n];
        float4 rb = *(const float4*)(bboxes + (long)n * 4);
        const float wr = rb.z - rb.x + 1.f, hr = rb.w - rb.y + 1.f;
        const float cxr = 0.5f * (rb.x + rb.z), cyr = 0.5f * (rb.y + rb.w);
        float pos[4];
        pos[0] = __logf(fabsf((cx - cxr) / w) + 1e-3f);
        pos[1] = __logf(fabsf((cy - cyr) / h) + 1e-3f);
        pos[2] = __logf(w / wr);
        pos[3] = __logf(h / hr);
        float gate = bg_g;
#pragma unroll
        for (int p = 0; p < 4; p++) {
#pragma unroll
            for (int f = 0; f < 8; f++) {
                const float arg = pos[p] * rdm[f];
                gate += swg[p * 16 + f] * __sinf(arg)
                      + swg[p * 16 + f + 8] * __cosf(arg);
            }
        }
        const float logit = aff + __logf(fmaxf(gate, 0.f) + 1e-6f);
        lg[n] = logit;
        m = fmaxf(m, logit);
    }
#pragma unroll
    for (int o = 32; o > 0; o >>= 1) m = fmaxf(m, __shfl_down(m, o));
    if ((t & 63) == 0) sred[t >> 6] = m;
    __syncthreads();
    if (t == 0) sMS = fmaxf(fmaxf(sred[0], sred[1]), fmaxf(sred[2], sred[3]));
    __syncthreads();
    m = sMS;
    __syncthreads();

    float s = 0.f;
    for (int n = t; n < N_PTS; n += 256) {
        const float e = __expf(lg[n] - m);
        lg[n] = e;
        s += e;
    }
#pragma unroll
    for (int o = 32; o > 0; o >>= 1) s += __shfl_down(s, o);
    if ((t & 63) == 0) sred[t >> 6] = s;
    __syncthreads();
    if (t == 0) sMS = sred[0] + sred[1] + sred[2] + sred[3];
    __syncthreads();
    const float inv = 1.0f / sMS;
    __syncthreads();

    unsigned short* orow = (unsigned short*)rowp;
    for (int n = t; n < WSTR; n += 256)
        orow[n] = (n < N_PTS) ? f2bf(lg[n] * inv) : (unsigned short)0;
}

// ---------------------------------------------------------------------------
extern "C" void kernel_launch(void* const* d_in, const int* in_sizes, int n_in,
                              void* d_out, int out_size, void* d_ws, size_t ws_size,
                              hipStream_t stream)
{
    const float* feat   = (const float*)d_in[0];
    const float* bboxes = (const float*)d_in[1];
    const float* Wq     = (const float*)d_in[2];
    const float* bq     = (const float*)d_in[3];
    const float* Wk     = (const float*)d_in[4];
    const float* bk     = (const float*)d_in[5];
    const float* Wg     = (const float*)d_in[6];
    const float* bg     = (const float*)d_in[7];
    const float* Wv     = (const float*)d_in[8];
    const float* bv     = (const float*)d_in[9];
    float* out = (float*)d_out;
    float* ws  = (float*)d_ws;

    // ws layout (float offsets), peak ~185.1 MB (same as R7):
    //  [0 .. 36,000,000)  drec 6000x6000. Dead after FPS; then reused:
    //      W     [0, 28,876,800)            4800 x 6016 logits (fp32 -> bf16 in place)
    //      kk_b  [28,900,000, 31,972,000)   6000x1024 bf16
    //      q_b   [31,972,000, 32,125,600)   300x1024 bf16
    //      roi_b [32,125,600, 32,279,200)   300x1024 bf16
    //      featT [32,300,000, 35,380,192)   1024x6016 bf16 (written post-FPS)
    //  [36,000,000 .. 45,216,000)  X=[hi|mid|lo] 6000x3072 bf16
    //      -> outt fp32 4800x1024 reuses [36,000,000, 40,915,200) after kk/gather
    //  [45,216,000 .. 45,740,288)  Wq_b
    //  [45,740,288 .. 46,264,576)  Wk_b
    //  [46,264,576 .. 46,270,576)  sqn
    //  [46,270,576 .. )            idx (300 ints)
    float* drec = ws;
    float* W    = ws;
    unsigned short* kk_b  = (unsigned short*)(ws + 28900000);
    unsigned short* q_b   = (unsigned short*)(ws + 31972000);
    unsigned short* roi_b = (unsigned short*)(ws + 32125600);
    unsigned short* featT = (unsigned short*)(ws + 32300000);
    unsigned short* X     = (unsigned short*)(ws + 36000000);
    float* outt           = ws + 36000000;
    unsigned short* Wq_b  = (unsigned short*)(ws + 45216000);
    unsigned short* Wk_b  = (unsigned short*)(ws + 45740288);
    float* sqnbuf         = ws + 46264576;
    int*   idxbuf         = (int*)(ws + 46270576);
    if (ws_size < (size_t)185100000) return;

    sqnpack3_kernel<<<N_PTS, 256, 0, stream>>>(feat, X, sqnbuf);
    wconv2_kernel<<<2048, 256, 0, stream>>>(Wq, Wk, Wq_b, Wk_b);

    // Gram: 3-way split bf16, 6 chunk passes, triangular grid, LDS epilogue
    mfma_gemm<true, false><<<1128, 256, 0, stream>>>(
        X, XSTR, 0, X, XSTR, 0, drec, N_PTS, 0,
        N_PTS, N_PTS, 6144, nullptr, 0, 1.f, sqnbuf, 47);

    fps_kernel<<<1, FPS_T, 0, stream>>>(drec, idxbuf);

    // featT goes into dead drec space -> must run after FPS
    transpose_kernel<<<dim3(32, 188), 256, 0, stream>>>(feat, featT);
    gatherb_kernel<<<KSEL, 256, 0, stream>>>(X, idxbuf, roi_b);

    // q = roi @ Wq^T + bq  (bf16 out)
    mfma_gemm<false, true><<<dim3(8, 3, 1), 256, 0, stream>>>(
        roi_b, 1024, 0, Wq_b, 1024, 0, q_b, 1024, 0,
        KSEL, DIM, DIM, bq, 0, 1.f, nullptr, 0);
    // kk = feat @ Wk^T + bk  (bf16 out; A = hi part of X, lda XSTR)
    mfma_gemm<false, true><<<dim3(8, 47, 1), 256, 0, stream>>>(
        X, XSTR, 0, Wk_b, 1024, 0, kk_b, 1024, 0,
        N_PTS, DIM, DIM, bk, 0, 1.f, nullptr, 0);

    // aff = (q . kk^T)/8 per group -> W fp32  (batched z=16, K=64)
    mfma_gemm<false, false><<<dim3(47, 3, GG), 256, 0, stream>>>(
        q_b, 1024, 64, kk_b, 1024, 64, W, (long)GG * WSTR, WSTR,
        KSEL, N_PTS, 64, nullptr, 0, 0.125f, nullptr, 0);

    // fused gate + softmax; W rows become bf16 probs in place
    gatesoftmax_kernel<<<KSEL * GG, 256, 0, stream>>>(bboxes, idxbuf, Wg, bg, W);

    // out_t = P @ feat  (A = bf16 probs in place, lda 2*WSTR shorts; B = featT)
    mfma_gemm<false, false><<<dim3(8, 38, 1), 256, 0, stream>>>(
        (unsigned short*)W, 2 * WSTR, 0, featT, WSTR, 0, outt, DIM, 0,
        KSEL * GG, DIM, WSTR, nullptr, 0, 1.f, nullptr, 0);

    // out = out_t . Wv + bv (fp32, small)
    sgemm_kernel<true><<<dim3(1, 3, GG), 256, 0, stream>>>(
        outt, (long)GG * DIM, DIM, Wv, DIM, (long)DGR * DIM, out, DIM, DGR,
        KSEL, DGR, DIM, bv, DGR, 1.f);
}

// Round 10
// 1365.589 us; speedup vs baseline: 1.2125x; 1.2125x over previous
//
#include <hip/hip_runtime.h>
#include <math.h>

#define N_PTS 6000
#define DIM   1024
#define KSEL  300
#define GG    16
#define DGR   64
#define WSTR  6016   // padded row stride for logits W (6000 -> 6016)
#define XSTR  2048   // X = [hi|lo] f16 2-way split, row stride

typedef _Float16 half8 __attribute__((ext_vector_type(8)));
typedef float floatx4 __attribute__((ext_vector_type(4)));

__device__ __forceinline__ unsigned short f2h(float x) {
    _Float16 h = (_Float16)x;                   // v_cvt_f16_f32, RNE
    return __builtin_bit_cast(unsigned short, h);
}
__device__ __forceinline__ float h2f(unsigned short u) {
    return (float)__builtin_bit_cast(_Float16, u);
}

__device__ __forceinline__ void async_copy16(const void* gsrc, void* ldst) {
    __builtin_amdgcn_global_load_lds(
        (const __attribute__((address_space(1))) void*)gsrc,
        (__attribute__((address_space(3))) void*)ldst,
        16, 0, 0);
}

// ---------------------------------------------------------------------------
// MFMA f16 GEMM, NT: C[i][j] = scale * sum_k A[i,k]*B[j,k] (+bias[j])
// 128x128 tile, BK=32, 256 threads (4 waves, each 64x64 = 4x4 16x16 tiles).
// GRAM: A=B=X=[hi|lo] f16 (lda 2048); 3 chunk passes with COMPILE-TIME part
//       offsets (hi.hi + hi.lo + lo.hi == x.y to ~fp32 accuracy: missing
//       lo.lo ~ 1024*2^-24 ~ 6e-5, same as fp32 accumulation noise);
//       triangular grid (bi<=bj), 1/cdist epilogue + mirrored store
//       (R7 epilogue — R8 NT starved fps, R9 LDS epilogue cost occupancy).
// OF16: store output as f16 (for q, kk feeding the aff MFMA).
// ---------------------------------------------------------------------------
template<bool GRAM, bool OF16>
__global__ __launch_bounds__(256)
void mfma_gemm(const void* Av, long lda, long az,
               const void* Bv, long ldb, long bz,
               void* Cv, long ldc, long cz,
               int M, int N, int Kd,
               const float* __restrict__ bias, long biasz,
               float scale, const float* __restrict__ sqn, int nbm)
{
    __shared__ unsigned short As[128 * 32];
    __shared__ unsigned short Bs[128 * 32];
    const int t = threadIdx.x;
    const int w = t >> 6, l = t & 63;
    const int wr = w >> 1, wc = w & 1;

    int row0, col0, bi = 0, bj = 0;
    if (GRAM) {
        int tt = blockIdx.x, rem = nbm;
        while (tt >= rem) { tt -= rem; bi++; rem--; }
        bj = bi + tt;
        row0 = bi * 128; col0 = bj * 128;
    } else {
        row0 = blockIdx.y * 128; col0 = blockIdx.x * 128;
    }
    const int z = blockIdx.z;
    const unsigned short* Ab = (const unsigned short*)Av + (long)z * az;
    const unsigned short* Bb = (const unsigned short*)Bv + (long)z * bz;

    floatx4 acc[4][4];
#pragma unroll
    for (int i = 0; i < 4; i++)
#pragma unroll
        for (int j = 0; j < 4; j++) acc[i][j] = (floatx4){0.f, 0.f, 0.f, 0.f};

    // clamped staging row indices (hoisted out of the K loop)
    int ra0 = row0 + (w * 2 + 0) * 16 + (l >> 2); ra0 = ra0 < M ? ra0 : M - 1;
    int ra1 = row0 + (w * 2 + 1) * 16 + (l >> 2); ra1 = ra1 < M ? ra1 : M - 1;
    int rb0 = col0 + (w * 2 + 0) * 16 + (l >> 2); rb0 = rb0 < N ? rb0 : N - 1;
    int rb1 = col0 + (w * 2 + 1) * 16 + (l >> 2); rb1 = rb1 < N ? rb1 : N - 1;
    const long lane_off = (l & 3) * 8;
    const unsigned short* gA0 = Ab + (long)ra0 * lda + lane_off;
    const unsigned short* gA1 = Ab + (long)ra1 * lda + lane_off;
    const unsigned short* gB0 = Bb + (long)rb0 * ldb + lane_off;
    const unsigned short* gB1 = Bb + (long)rb1 * ldb + lane_off;
    unsigned short* lA0 = As + ((w * 2 + 0) * 16) * 32;
    unsigned short* lA1 = As + ((w * 2 + 1) * 16) * 32;
    unsigned short* lB0 = Bs + ((w * 2 + 0) * 16) * 32;
    unsigned short* lB1 = Bs + ((w * 2 + 1) * 16) * 32;

    auto kstep = [&](long offA, long offB) {
        async_copy16(gA0 + offA, (void*)lA0);
        async_copy16(gA1 + offA, (void*)lA1);
        async_copy16(gB0 + offB, (void*)lB0);
        async_copy16(gB1 + offB, (void*)lB1);
        __syncthreads();
        half8 af[4], bfr[4];
#pragma unroll
        for (int ti = 0; ti < 4; ti++)
            af[ti] = *(const half8*)(As + (wr * 64 + ti * 16 + (l & 15)) * 32 + (l >> 4) * 8);
#pragma unroll
        for (int tj = 0; tj < 4; tj++)
            bfr[tj] = *(const half8*)(Bs + (wc * 64 + tj * 16 + (l & 15)) * 32 + (l >> 4) * 8);
#pragma unroll
        for (int ti = 0; ti < 4; ti++)
#pragma unroll
            for (int tj = 0; tj < 4; tj++)
                acc[ti][tj] = __builtin_amdgcn_mfma_f32_16x16x32_f16(
                    af[ti], bfr[tj], acc[ti][tj], 0, 0, 0);
        __syncthreads();
    };

    if (GRAM) {
        // 3 chunk passes, compile-time part offsets (hi=0, lo=1024)
#pragma unroll 1
        for (int k0 = 0; k0 < 1024; k0 += 32) kstep(k0, k0);              // hi.hi
#pragma unroll 1
        for (int k0 = 0; k0 < 1024; k0 += 32) kstep(k0, k0 + 1024);      // hi.lo
#pragma unroll 1
        for (int k0 = 0; k0 < 1024; k0 += 32) kstep(k0 + 1024, k0);      // lo.hi
    } else {
#pragma unroll 1
        for (int k0 = 0; k0 < Kd; k0 += 32) kstep(k0, k0);
    }

    float* Cf = (float*)Cv + (long)z * cz;
    unsigned short* Ch = (unsigned short*)Cv + (long)z * cz;
    const float* bias_p = bias ? bias + (long)z * biasz : nullptr;
#pragma unroll
    for (int ti = 0; ti < 4; ti++) {
#pragma unroll
        for (int tj = 0; tj < 4; tj++) {
            const int c = col0 + wc * 64 + tj * 16 + (l & 15);
            const int rb = row0 + wr * 64 + ti * 16 + (l >> 4) * 4;
            if (GRAM) {
                float rec4[4];
#pragma unroll
                for (int reg = 0; reg < 4; reg++) {
                    int r = rb + reg;
                    if (r >= M || c >= N) { rec4[reg] = 0.f; continue; }
                    if (r == c) { rec4[reg] = INFINITY; }
                    else {
                        float sq = sqn[r] + sqn[c] - 2.f * acc[ti][tj][reg];
                        rec4[reg] = 1.0f / sqrtf(fmaxf(sq, 0.f));
                    }
                    Cf[(long)r * ldc + c] = rec4[reg];
                }
                if (bi != bj && c < N && rb + 3 < M) {  // mirrored float4 store
                    *(float4*)(Cf + (long)c * ldc + rb) =
                        make_float4(rec4[0], rec4[1], rec4[2], rec4[3]);
                }
            } else {
#pragma unroll
                for (int reg = 0; reg < 4; reg++) {
                    int r = rb + reg;
                    if (r >= M || c >= N) continue;
                    float v = acc[ti][tj][reg] * scale;
                    if (bias_p) v += bias_p[c];
                    if (OF16) Ch[(long)r * ldc + c] = f2h(v);
                    else      Cf[(long)r * ldc + c] = v;
                }
            }
        }
    }
}

// ---------------------------------------------------------------------------
// fp32 SGEMM kept for the small Wv projection only.
// ---------------------------------------------------------------------------
#define BM 128
#define BN 128
#define BKK 8
#define TM 8
#define TN 8

template<bool TRANSB>
__global__ __launch_bounds__(256)
void sgemm_kernel(const float* __restrict__ A, long lda, long az,
                  const float* __restrict__ B, long ldb, long bz,
                  float* __restrict__ C, long ldc, long cz,
                  int M, int N, int Kd,
                  const float* __restrict__ bias, long biasz, float scale)
{
    __shared__ float As[BKK][BM];
    __shared__ float Bs[BKK][BN];
    const int t = threadIdx.x;
    const int z = blockIdx.z;
    A += (long)z * az; B += (long)z * bz; C += (long)z * cz;
    const float* bias_p = bias ? (bias + (long)z * biasz) : nullptr;
    const int row0 = blockIdx.y * BM;
    const int col0 = blockIdx.x * BN;
    const int tx = t & 15, ty = t >> 4;

    float acc[TM][TN];
#pragma unroll
    for (int i = 0; i < TM; i++)
#pragma unroll
        for (int j = 0; j < TN; j++) acc[i][j] = 0.f;

    const int lrow = t >> 1;
    const int lcol = (t & 1) * 4;

    for (int k0 = 0; k0 < Kd; k0 += BKK) {
        {
            int r = row0 + lrow; r = (r < M) ? r : (M - 1);
            float4 v = *(const float4*)(A + (long)r * lda + (k0 + lcol));
            As[lcol + 0][lrow] = v.x; As[lcol + 1][lrow] = v.y;
            As[lcol + 2][lrow] = v.z; As[lcol + 3][lrow] = v.w;
        }
        {
            int r = col0 + lrow; r = (r < N) ? r : (N - 1);
            float4 v = *(const float4*)(B + (long)r * ldb + (k0 + lcol));
            Bs[lcol + 0][lrow] = v.x; Bs[lcol + 1][lrow] = v.y;
            Bs[lcol + 2][lrow] = v.z; Bs[lcol + 3][lrow] = v.w;
        }
        __syncthreads();
#pragma unroll
        for (int kk = 0; kk < BKK; kk++) {
            float a[TM], b[TN];
#pragma unroll
            for (int i = 0; i < TM; i++) a[i] = As[kk][ty * TM + i];
#pragma unroll
            for (int j = 0; j < TN; j++) b[j] = Bs[kk][tx * TN + j];
#pragma unroll
            for (int i = 0; i < TM; i++)
#pragma unroll
                for (int j = 0; j < TN; j++)
                    acc[i][j] = fmaf(a[i], b[j], acc[i][j]);
        }
        __syncthreads();
    }
#pragma unroll
    for (int i = 0; i < TM; i++) {
        int r = row0 + ty * TM + i;
        if (r >= M) continue;
#pragma unroll
        for (int j = 0; j < TN; j++) {
            int c = col0 + tx * TN + j;
            if (c >= N) continue;
            float v = acc[i][j] * scale;
            if (bias_p) v += bias_p[c];
            C[(long)r * ldc + c] = v;
        }
    }
}

// ---------------------------------------------------------------------------
// Fused: sqn[r] = ||feat[r]||^2  AND  X = [hi|lo] f16 2-way split.
// ---------------------------------------------------------------------------
__global__ __launch_bounds__(256)
void sqnpack2_kernel(const float* __restrict__ feat,
                     unsigned short* __restrict__ X, float* __restrict__ sqn)
{
    const int r = blockIdx.x, t = threadIdx.x;
    float4 v = *(const float4*)(feat + (long)r * DIM + t * 4);
    float s = v.x * v.x + v.y * v.y + v.z * v.z + v.w * v.w;

    ushort4 hi, lo;
    hi.x = f2h(v.x); lo.x = f2h(v.x - h2f(hi.x));
    hi.y = f2h(v.y); lo.y = f2h(v.y - h2f(hi.y));
    hi.z = f2h(v.z); lo.z = f2h(v.z - h2f(hi.z));
    hi.w = f2h(v.w); lo.w = f2h(v.w - h2f(hi.w));
    *(ushort4*)(X + (long)r * XSTR + t * 4) = hi;
    *(ushort4*)(X + (long)r * XSTR + 1024 + t * 4) = lo;

#pragma unroll
    for (int o = 32; o > 0; o >>= 1) s += __shfl_down(s, o);
    __shared__ float sr[4];
    if ((t & 63) == 0) sr[t >> 6] = s;
    __syncthreads();
    if (t == 0) sqn[r] = sr[0] + sr[1] + sr[2] + sr[3];
}

// Both weight conversions in one launch: blocks [0,1024) -> Wq, [1024,2048) -> Wk
__global__ __launch_bounds__(256)
void wconv2_kernel(const float* __restrict__ Wq, const float* __restrict__ Wk,
                   unsigned short* __restrict__ Wq_h, unsigned short* __restrict__ Wk_h)
{
    const int b = blockIdx.x;
    const float* src = (b < 1024) ? Wq : Wk;
    unsigned short* dst = (b < 1024) ? Wq_h : Wk_h;
    const long i = ((long)(b & 1023) * 256 + threadIdx.x) * 4;
    float4 v = *(const float4*)(src + i);
    ushort4 o;
    o.x = f2h(v.x); o.y = f2h(v.y); o.z = f2h(v.z); o.w = f2h(v.w);
    *(ushort4*)(dst + i) = o;
}

// featT[d][r] = f16(feat[r][d]), 1024 x 6016 (cols 6000..6015 zero)
__global__ __launch_bounds__(256)
void transpose_kernel(const float* __restrict__ feat, unsigned short* __restrict__ featT)
{
    __shared__ unsigned short tile[32][33];
    const int bx = blockIdx.x;   // d-block 0..31
    const int by = blockIdx.y;   // r-block 0..187
    const int t = threadIdx.x;
    const int lr = t >> 3;
    const int lc = (t & 7) * 4;
    const int r = by * 32 + lr;
    if (r < N_PTS) {
        float4 v = *(const float4*)(feat + (long)r * DIM + bx * 32 + lc);
        tile[lr][lc + 0] = f2h(v.x); tile[lr][lc + 1] = f2h(v.y);
        tile[lr][lc + 2] = f2h(v.z); tile[lr][lc + 3] = f2h(v.w);
    } else {
        tile[lr][lc + 0] = 0; tile[lr][lc + 1] = 0;
        tile[lr][lc + 2] = 0; tile[lr][lc + 3] = 0;
    }
    __syncthreads();
    const int orow = bx * 32 + lr;
    ushort4 o;
    o.x = tile[lc + 0][lr]; o.y = tile[lc + 1][lr];
    o.z = tile[lc + 2][lr]; o.w = tile[lc + 3][lr];
    *(ushort4*)(featT + (long)orow * WSTR + by * 32 + lc) = o;
}

// ---------------------------------------------------------------------------
// Greedy FPS — R4 reduction, float4 load path (R7, measured-good).
// ---------------------------------------------------------------------------
#define FPS_T 1024

__global__ __launch_bounds__(1024)
void fps_kernel(const float* __restrict__ Drec, int* __restrict__ idxout)
{
    const int t = threadIdx.x;
    const bool act = t < 750;
    float ds[8];
    if (act) {
        const float4* p = (const float4*)Drec + 2 * t;
        float4 a0 = p[0], a1 = p[1];
        ds[0] = a0.x; ds[1] = a0.y; ds[2] = a0.z; ds[3] = a0.w;
        ds[4] = a1.x; ds[5] = a1.y; ds[6] = a1.z; ds[7] = a1.w;
    } else {
#pragma unroll
        for (int j = 0; j < 8; j++) ds[j] = INFINITY;
    }
    __shared__ unsigned long long red[16];
    __shared__ int s_sel;
    if (t == 0) idxout[0] = 0;

    for (int it = 1; it < KSEL; it++) {
        float mv = ds[0]; int mi = 8 * t;
#pragma unroll
        for (int j = 1; j < 8; j++) {
            if (ds[j] < mv) { mv = ds[j]; mi = 8 * t + j; }
        }
        unsigned long long key = act
            ? (((unsigned long long)__float_as_uint(mv) << 32) | (unsigned)mi)
            : ~0ull;
#pragma unroll
        for (int o = 32; o > 0; o >>= 1) {
            unsigned long long other = __shfl_down(key, o);
            if (other < key) key = other;
        }
        if ((t & 63) == 0) red[t >> 6] = key;
        __syncthreads();
        if (t < 64) {
            unsigned long long k2 = (t < 16) ? red[t] : ~0ull;
#pragma unroll
            for (int o = 8; o > 0; o >>= 1) {
                unsigned long long other = __shfl_down(k2, o);
                if (other < k2) k2 = other;
            }
            if (t == 0) s_sel = (int)(unsigned)(k2 & 0xffffffffull);
        }
        __syncthreads();
        const int sel = s_sel;
        if (t == 0) idxout[it] = sel;
        if (act) {
            const float4* rp = (const float4*)(Drec + (long)sel * N_PTS) + 2 * t;
            float4 r0 = rp[0], r1 = rp[1];
            ds[0] += r0.x; ds[1] += r0.y; ds[2] += r0.z; ds[3] += r0.w;
            ds[4] += r1.x; ds[5] += r1.y; ds[6] += r1.z; ds[7] += r1.w;
        }
    }
}

__global__ __launch_bounds__(256)
void gatherb_kernel(const unsigned short* __restrict__ X, const int* __restrict__ idx,
                    unsigned short* __restrict__ roi)
{
    const int k = blockIdx.x, t = threadIdx.x;
    const unsigned short* src = X + (long)idx[k] * XSTR;   // hi part
    *(ushort4*)(roi + (long)k * DIM + t * 4) = *(const ushort4*)(src + t * 4);
}

// ---------------------------------------------------------------------------
// Fused gate + softmax: one block per (k,g) row of W (in-place fp32 -> f16).
// ---------------------------------------------------------------------------
__global__ __launch_bounds__(256)
void gatesoftmax_kernel(const float* __restrict__ bboxes,
                        const int* __restrict__ idx,
                        const float* __restrict__ Wg,
                        const float* __restrict__ bgp,
                        float* __restrict__ W)
{
    __shared__ float lg[WSTR];      // 24 KB: logits, then exp values
    __shared__ float swg[64];
    __shared__ float sred[4];
    __shared__ float sbb[4];
    __shared__ float sMS;
    const int t = threadIdx.x;
    const int row = blockIdx.x;     // k*GG + g
    const int k = row >> 4, g = row & 15;
    float* rowp = W + (long)row * WSTR;

    if (t < 64) swg[t] = Wg[g * 64 + t];
    if (t < 4)  sbb[t] = bboxes[(long)idx[k] * 4 + t];
    __syncthreads();

    const float x1 = sbb[0], y1 = sbb[1], x2 = sbb[2], y2 = sbb[3];
    const float w  = x2 - x1 + 1.f, h = y2 - y1 + 1.f;
    const float cx = 0.5f * (x1 + x2), cy = 0.5f * (y1 + y2);
    const float bg_g = bgp[g];
    const float rdm[8] = { 100.0f, 42.169650342858226f, 17.782794100389228f,
                           7.498942093324559f, 3.1622776601683795f,
                           1.333521432163324f, 0.5623413251903491f,
                           0.23713737056616552f };

    float m = -INFINITY;
    for (int n = t; n < N_PTS; n += 256) {
        const float aff = rowp[n];
        float4 rb = *(const float4*)(bboxes + (long)n * 4);
        const float wr = rb.z - rb.x + 1.f, hr = rb.w - rb.y + 1.f;
        const float cxr = 0.5f * (rb.x + rb.z), cyr = 0.5f * (rb.y + rb.w);
        float pos[4];
        pos[0] = __logf(fabsf((cx - cxr) / w) + 1e-3f);
        pos[1] = __logf(fabsf((cy - cyr) / h) + 1e-3f);
        pos[2] = __logf(w / wr);
        pos[3] = __logf(h / hr);
        float gate = bg_g;
#pragma unroll
        for (int p = 0; p < 4; p++) {
#pragma unroll
            for (int f = 0; f < 8; f++) {
                const float arg = pos[p] * rdm[f];
                gate += swg[p * 16 + f] * __sinf(arg)
                      + swg[p * 16 + f + 8] * __cosf(arg);
            }
        }
        const float logit = aff + __logf(fmaxf(gate, 0.f) + 1e-6f);
        lg[n] = logit;
        m = fmaxf(m, logit);
    }
#pragma unroll
    for (int o = 32; o > 0; o >>= 1) m = fmaxf(m, __shfl_down(m, o));
    if ((t & 63) == 0) sred[t >> 6] = m;
    __syncthreads();
    if (t == 0) sMS = fmaxf(fmaxf(sred[0], sred[1]), fmaxf(sred[2], sred[3]));
    __syncthreads();
    m = sMS;
    __syncthreads();

    float s = 0.f;
    for (int n = t; n < N_PTS; n += 256) {
        const float e = __expf(lg[n] - m);
        lg[n] = e;
        s += e;
    }
#pragma unroll
    for (int o = 32; o > 0; o >>= 1) s += __shfl_down(s, o);
    if ((t & 63) == 0) sred[t >> 6] = s;
    __syncthreads();
    if (t == 0) sMS = sred[0] + sred[1] + sred[2] + sred[3];
    __syncthreads();
    const float inv = 1.0f / sMS;
    __syncthreads();

    unsigned short* orow = (unsigned short*)rowp;
    for (int n = t; n < WSTR; n += 256)
        orow[n] = (n < N_PTS) ? f2h(lg[n] * inv) : (unsigned short)0;
}

// ---------------------------------------------------------------------------
extern "C" void kernel_launch(void* const* d_in, const int* in_sizes, int n_in,
                              void* d_out, int out_size, void* d_ws, size_t ws_size,
                              hipStream_t stream)
{
    const float* feat   = (const float*)d_in[0];
    const float* bboxes = (const float*)d_in[1];
    const float* Wq     = (const float*)d_in[2];
    const float* bq     = (const float*)d_in[3];
    const float* Wk     = (const float*)d_in[4];
    const float* bk     = (const float*)d_in[5];
    const float* Wg     = (const float*)d_in[6];
    const float* bg     = (const float*)d_in[7];
    const float* Wv     = (const float*)d_in[8];
    const float* bv     = (const float*)d_in[9];
    float* out = (float*)d_out;
    float* ws  = (float*)d_ws;

    // ws layout (float offsets), peak ~185.1 MB (same bound as R7):
    //  [0 .. 36,000,000)  drec 6000x6000. Dead after FPS; then reused:
    //      W     [0, 28,876,800)            4800 x 6016 logits (fp32 -> f16 in place)
    //      kk_h  [28,900,000, 31,972,000)   6000x1024 f16
    //      q_h   [31,972,000, 32,125,600)   300x1024 f16
    //      roi_h [32,125,600, 32,279,200)   300x1024 f16
    //      featT [32,300,000, 35,380,192)   1024x6016 f16 (written post-FPS)
    //  [36,000,000 .. 42,144,000)  X=[hi|lo] 6000x2048 f16
    //      -> outt fp32 4800x1024 reuses [36,000,000, 40,915,200) after kk/gather
    //  [45,216,000 .. 45,740,288)  Wq_h
    //  [45,740,288 .. 46,264,576)  Wk_h
    //  [46,264,576 .. 46,270,576)  sqn
    //  [46,270,576 .. )            idx (300 ints)
    float* drec = ws;
    float* W    = ws;
    unsigned short* kk_h  = (unsigned short*)(ws + 28900000);
    unsigned short* q_h   = (unsigned short*)(ws + 31972000);
    unsigned short* roi_h = (unsigned short*)(ws + 32125600);
    unsigned short* featT = (unsigned short*)(ws + 32300000);
    unsigned short* X     = (unsigned short*)(ws + 36000000);
    float* outt           = ws + 36000000;
    unsigned short* Wq_h  = (unsigned short*)(ws + 45216000);
    unsigned short* Wk_h  = (unsigned short*)(ws + 45740288);
    float* sqnbuf         = ws + 46264576;
    int*   idxbuf         = (int*)(ws + 46270576);
    if (ws_size < (size_t)185100000) return;

    sqnpack2_kernel<<<N_PTS, 256, 0, stream>>>(feat, X, sqnbuf);
    wconv2_kernel<<<2048, 256, 0, stream>>>(Wq, Wk, Wq_h, Wk_h);

    // Gram: 2-way f16 split, 3 chunk passes (K=3072), triangular grid
    mfma_gemm<true, false><<<1128, 256, 0, stream>>>(
        X, XSTR, 0, X, XSTR, 0, drec, N_PTS, 0,
        N_PTS, N_PTS, 3072, nullptr, 0, 1.f, sqnbuf, 47);

    fps_kernel<<<1, FPS_T, 0, stream>>>(drec, idxbuf);

    // featT goes into dead drec space -> must run after FPS
    transpose_kernel<<<dim3(32, 188), 256, 0, stream>>>(feat, featT);
    gatherb_kernel<<<KSEL, 256, 0, stream>>>(X, idxbuf, roi_h);

    // q = roi @ Wq^T + bq  (f16 out)
    mfma_gemm<false, true><<<dim3(8, 3, 1), 256, 0, stream>>>(
        roi_h, 1024, 0, Wq_h, 1024, 0, q_h, 1024, 0,
        KSEL, DIM, DIM, bq, 0, 1.f, nullptr, 0);
    // kk = feat @ Wk^T + bk  (f16 out; A = hi part of X, lda XSTR)
    mfma_gemm<false, true><<<dim3(8, 47, 1), 256, 0, stream>>>(
        X, XSTR, 0, Wk_h, 1024, 0, kk_h, 1024, 0,
        N_PTS, DIM, DIM, bk, 0, 1.f, nullptr, 0);

    // aff = (q . kk^T)/8 per group -> W fp32  (batched z=16, K=64)
    mfma_gemm<false, false><<<dim3(47, 3, GG), 256, 0, stream>>>(
        q_h, 1024, 64, kk_h, 1024, 64, W, (long)GG * WSTR, WSTR,
        KSEL, N_PTS, 64, nullptr, 0, 0.125f, nullptr, 0);

    // fused gate + softmax; W rows become f16 probs in place
    gatesoftmax_kernel<<<KSEL * GG, 256, 0, stream>>>(bboxes, idxbuf, Wg, bg, W);

    // out_t = P @ feat  (A = f16 probs in place, lda 2*WSTR shorts; B = featT)
    mfma_gemm<false, false><<<dim3(8, 38, 1), 256, 0, stream>>>(
        (unsigned short*)W, 2 * WSTR, 0, featT, WSTR, 0, outt, DIM, 0,
        KSEL * GG, DIM, WSTR, nullptr, 0, 1.f, nullptr, 0);

    // out = out_t . Wv + bv (fp32, small)
    sgemm_kernel<true><<<dim3(1, 3, GG), 256, 0, stream>>>(
        outt, (long)GG * DIM, DIM, Wv, DIM, (long)DGR * DIM, out, DIM, DGR,
        KSEL, DGR, DIM, bv, DGR, 1.f);
}

// Round 11
// 1226.914 us; speedup vs baseline: 1.3496x; 1.1130x over previous
//
#include <hip/hip_runtime.h>
#include <math.h>

#define N_PTS 6000
#define DIM   1024
#define KSEL  300
#define GG    16
#define DGR   64
#define WSTR  6016   // padded row stride for logits W (6000 -> 6016)
#define XSTR  2048   // X = [hi|lo] f16 2-way split, row stride

typedef _Float16 half8 __attribute__((ext_vector_type(8)));
typedef float floatx4 __attribute__((ext_vector_type(4)));

__device__ __forceinline__ unsigned short f2h(float x) {
    _Float16 h = (_Float16)x;                   // v_cvt_f16_f32, RNE
    return __builtin_bit_cast(unsigned short, h);
}
__device__ __forceinline__ float h2f(unsigned short u) {
    return (float)__builtin_bit_cast(_Float16, u);
}

__device__ __forceinline__ void async_copy16(const void* gsrc, void* ldst) {
    __builtin_amdgcn_global_load_lds(
        (const __attribute__((address_space(1))) void*)gsrc,
        (__attribute__((address_space(3))) void*)ldst,
        16, 0, 0);
}

// ---------------------------------------------------------------------------
// MFMA f16 GEMM, NT: C[i][j] = scale * sum_k A[i,k]*B[j,k] (+bias[j])
// 128x128 tile, BK=32, 256 threads (4 waves, each 64x64 = 4x4 16x16 tiles).
// GRAM: A=B=X=[hi|lo] f16 (lda 2048); 3 chunk passes (hi.hi + hi.lo + lo.hi
//       == x.y to ~fp32 accuracy); triangular grid, 1/cdist epilogue +
//       mirrored store (R7 epilogue — NT and LDS variants both regressed).
// OF16: store output as f16 (for q, kk feeding the aff MFMA).
// ---------------------------------------------------------------------------
template<bool GRAM, bool OF16>
__global__ __launch_bounds__(256)
void mfma_gemm(const void* Av, long lda, long az,
               const void* Bv, long ldb, long bz,
               void* Cv, long ldc, long cz,
               int M, int N, int Kd,
               const float* __restrict__ bias, long biasz,
               float scale, const float* __restrict__ sqn, int nbm)
{
    __shared__ unsigned short As[128 * 32];
    __shared__ unsigned short Bs[128 * 32];
    const int t = threadIdx.x;
    const int w = t >> 6, l = t & 63;
    const int wr = w >> 1, wc = w & 1;

    int row0, col0, bi = 0, bj = 0;
    if (GRAM) {
        int tt = blockIdx.x, rem = nbm;
        while (tt >= rem) { tt -= rem; bi++; rem--; }
        bj = bi + tt;
        row0 = bi * 128; col0 = bj * 128;
    } else {
        row0 = blockIdx.y * 128; col0 = blockIdx.x * 128;
    }
    const int z = blockIdx.z;
    const unsigned short* Ab = (const unsigned short*)Av + (long)z * az;
    const unsigned short* Bb = (const unsigned short*)Bv + (long)z * bz;

    floatx4 acc[4][4];
#pragma unroll
    for (int i = 0; i < 4; i++)
#pragma unroll
        for (int j = 0; j < 4; j++) acc[i][j] = (floatx4){0.f, 0.f, 0.f, 0.f};

    // clamped staging row indices (hoisted out of the K loop)
    int ra0 = row0 + (w * 2 + 0) * 16 + (l >> 2); ra0 = ra0 < M ? ra0 : M - 1;
    int ra1 = row0 + (w * 2 + 1) * 16 + (l >> 2); ra1 = ra1 < M ? ra1 : M - 1;
    int rb0 = col0 + (w * 2 + 0) * 16 + (l >> 2); rb0 = rb0 < N ? rb0 : N - 1;
    int rb1 = col0 + (w * 2 + 1) * 16 + (l >> 2); rb1 = rb1 < N ? rb1 : N - 1;
    const long lane_off = (l & 3) * 8;
    const unsigned short* gA0 = Ab + (long)ra0 * lda + lane_off;
    const unsigned short* gA1 = Ab + (long)ra1 * lda + lane_off;
    const unsigned short* gB0 = Bb + (long)rb0 * ldb + lane_off;
    const unsigned short* gB1 = Bb + (long)rb1 * ldb + lane_off;
    unsigned short* lA0 = As + ((w * 2 + 0) * 16) * 32;
    unsigned short* lA1 = As + ((w * 2 + 1) * 16) * 32;
    unsigned short* lB0 = Bs + ((w * 2 + 0) * 16) * 32;
    unsigned short* lB1 = Bs + ((w * 2 + 1) * 16) * 32;

    auto kstep = [&](long offA, long offB) {
        async_copy16(gA0 + offA, (void*)lA0);
        async_copy16(gA1 + offA, (void*)lA1);
        async_copy16(gB0 + offB, (void*)lB0);
        async_copy16(gB1 + offB, (void*)lB1);
        __syncthreads();
        half8 af[4], bfr[4];
#pragma unroll
        for (int ti = 0; ti < 4; ti++)
            af[ti] = *(const half8*)(As + (wr * 64 + ti * 16 + (l & 15)) * 32 + (l >> 4) * 8);
#pragma unroll
        for (int tj = 0; tj < 4; tj++)
            bfr[tj] = *(const half8*)(Bs + (wc * 64 + tj * 16 + (l & 15)) * 32 + (l >> 4) * 8);
#pragma unroll
        for (int ti = 0; ti < 4; ti++)
#pragma unroll
            for (int tj = 0; tj < 4; tj++)
                acc[ti][tj] = __builtin_amdgcn_mfma_f32_16x16x32_f16(
                    af[ti], bfr[tj], acc[ti][tj], 0, 0, 0);
        __syncthreads();
    };

    if (GRAM) {
        // 3 chunk passes, compile-time part offsets (hi=0, lo=1024)
#pragma unroll 1
        for (int k0 = 0; k0 < 1024; k0 += 32) kstep(k0, k0);              // hi.hi
#pragma unroll 1
        for (int k0 = 0; k0 < 1024; k0 += 32) kstep(k0, k0 + 1024);      // hi.lo
#pragma unroll 1
        for (int k0 = 0; k0 < 1024; k0 += 32) kstep(k0 + 1024, k0);      // lo.hi
    } else {
#pragma unroll 1
        for (int k0 = 0; k0 < Kd; k0 += 32) kstep(k0, k0);
    }

    float* Cf = (float*)Cv + (long)z * cz;
    unsigned short* Ch = (unsigned short*)Cv + (long)z * cz;
    const float* bias_p = bias ? bias + (long)z * biasz : nullptr;
#pragma unroll
    for (int ti = 0; ti < 4; ti++) {
#pragma unroll
        for (int tj = 0; tj < 4; tj++) {
            const int c = col0 + wc * 64 + tj * 16 + (l & 15);
            const int rb = row0 + wr * 64 + ti * 16 + (l >> 4) * 4;
            if (GRAM) {
                float rec4[4];
#pragma unroll
                for (int reg = 0; reg < 4; reg++) {
                    int r = rb + reg;
                    if (r >= M || c >= N) { rec4[reg] = 0.f; continue; }
                    if (r == c) { rec4[reg] = INFINITY; }
                    else {
                        float sq = sqn[r] + sqn[c] - 2.f * acc[ti][tj][reg];
                        rec4[reg] = 1.0f / sqrtf(fmaxf(sq, 0.f));
                    }
                    Cf[(long)r * ldc + c] = rec4[reg];
                }
                if (bi != bj && c < N && rb + 3 < M) {  // mirrored float4 store
                    *(float4*)(Cf + (long)c * ldc + rb) =
                        make_float4(rec4[0], rec4[1], rec4[2], rec4[3]);
                }
            } else {
#pragma unroll
                for (int reg = 0; reg < 4; reg++) {
                    int r = rb + reg;
                    if (r >= M || c >= N) continue;
                    float v = acc[ti][tj][reg] * scale;
                    if (bias_p) v += bias_p[c];
                    if (OF16) Ch[(long)r * ldc + c] = f2h(v);
                    else      Cf[(long)r * ldc + c] = v;
                }
            }
        }
    }
}

// ---------------------------------------------------------------------------
// fp32 SGEMM kept for the small Wv projection only.
// ---------------------------------------------------------------------------
#define BM 128
#define BN 128
#define BKK 8
#define TM 8
#define TN 8

template<bool TRANSB>
__global__ __launch_bounds__(256)
void sgemm_kernel(const float* __restrict__ A, long lda, long az,
                  const float* __restrict__ B, long ldb, long bz,
                  float* __restrict__ C, long ldc, long cz,
                  int M, int N, int Kd,
                  const float* __restrict__ bias, long biasz, float scale)
{
    __shared__ float As[BKK][BM];
    __shared__ float Bs[BKK][BN];
    const int t = threadIdx.x;
    const int z = blockIdx.z;
    A += (long)z * az; B += (long)z * bz; C += (long)z * cz;
    const float* bias_p = bias ? (bias + (long)z * biasz) : nullptr;
    const int row0 = blockIdx.y * BM;
    const int col0 = blockIdx.x * BN;
    const int tx = t & 15, ty = t >> 4;

    float acc[TM][TN];
#pragma unroll
    for (int i = 0; i < TM; i++)
#pragma unroll
        for (int j = 0; j < TN; j++) acc[i][j] = 0.f;

    const int lrow = t >> 1;
    const int lcol = (t & 1) * 4;

    for (int k0 = 0; k0 < Kd; k0 += BKK) {
        {
            int r = row0 + lrow; r = (r < M) ? r : (M - 1);
            float4 v = *(const float4*)(A + (long)r * lda + (k0 + lcol));
            As[lcol + 0][lrow] = v.x; As[lcol + 1][lrow] = v.y;
            As[lcol + 2][lrow] = v.z; As[lcol + 3][lrow] = v.w;
        }
        {
            int r = col0 + lrow; r = (r < N) ? r : (N - 1);
            float4 v = *(const float4*)(B + (long)r * ldb + (k0 + lcol));
            Bs[lcol + 0][lrow] = v.x; Bs[lcol + 1][lrow] = v.y;
            Bs[lcol + 2][lrow] = v.z; Bs[lcol + 3][lrow] = v.w;
        }
        __syncthreads();
#pragma unroll
        for (int kk = 0; kk < BKK; kk++) {
            float a[TM], b[TN];
#pragma unroll
            for (int i = 0; i < TM; i++) a[i] = As[kk][ty * TM + i];
#pragma unroll
            for (int j = 0; j < TN; j++) b[j] = Bs[kk][tx * TN + j];
#pragma unroll
            for (int i = 0; i < TM; i++)
#pragma unroll
                for (int j = 0; j < TN; j++)
                    acc[i][j] = fmaf(a[i], b[j], acc[i][j]);
        }
        __syncthreads();
    }
#pragma unroll
    for (int i = 0; i < TM; i++) {
        int r = row0 + ty * TM + i;
        if (r >= M) continue;
#pragma unroll
        for (int j = 0; j < TN; j++) {
            int c = col0 + tx * TN + j;
            if (c >= N) continue;
            float v = acc[i][j] * scale;
            if (bias_p) v += bias_p[c];
            C[(long)r * ldc + c] = v;
        }
    }
}

// ---------------------------------------------------------------------------
// Fused: sqn[r] = ||feat[r]||^2  AND  X = [hi|lo] f16 2-way split.
// ---------------------------------------------------------------------------
__global__ __launch_bounds__(256)
void sqnpack2_kernel(const float* __restrict__ feat,
                     unsigned short* __restrict__ X, float* __restrict__ sqn)
{
    const int r = blockIdx.x, t = threadIdx.x;
    float4 v = *(const float4*)(feat + (long)r * DIM + t * 4);
    float s = v.x * v.x + v.y * v.y + v.z * v.z + v.w * v.w;

    ushort4 hi, lo;
    hi.x = f2h(v.x); lo.x = f2h(v.x - h2f(hi.x));
    hi.y = f2h(v.y); lo.y = f2h(v.y - h2f(hi.y));
    hi.z = f2h(v.z); lo.z = f2h(v.z - h2f(hi.z));
    hi.w = f2h(v.w); lo.w = f2h(v.w - h2f(hi.w));
    *(ushort4*)(X + (long)r * XSTR + t * 4) = hi;
    *(ushort4*)(X + (long)r * XSTR + 1024 + t * 4) = lo;

#pragma unroll
    for (int o = 32; o > 0; o >>= 1) s += __shfl_down(s, o);
    __shared__ float sr[4];
    if ((t & 63) == 0) sr[t >> 6] = s;
    __syncthreads();
    if (t == 0) sqn[r] = sr[0] + sr[1] + sr[2] + sr[3];
}

// Both weight conversions in one launch: blocks [0,1024) -> Wq, [1024,2048) -> Wk
__global__ __launch_bounds__(256)
void wconv2_kernel(const float* __restrict__ Wq, const float* __restrict__ Wk,
                   unsigned short* __restrict__ Wq_h, unsigned short* __restrict__ Wk_h)
{
    const int b = blockIdx.x;
    const float* src = (b < 1024) ? Wq : Wk;
    unsigned short* dst = (b < 1024) ? Wq_h : Wk_h;
    const long i = ((long)(b & 1023) * 256 + threadIdx.x) * 4;
    float4 v = *(const float4*)(src + i);
    ushort4 o;
    o.x = f2h(v.x); o.y = f2h(v.y); o.z = f2h(v.z); o.w = f2h(v.w);
    *(ushort4*)(dst + i) = o;
}

// featT[d][r] = f16(feat[r][d]), 1024 x 6016 (cols 6000..6015 zero)
__global__ __launch_bounds__(256)
void transpose_kernel(const float* __restrict__ feat, unsigned short* __restrict__ featT)
{
    __shared__ unsigned short tile[32][33];
    const int bx = blockIdx.x;   // d-block 0..31
    const int by = blockIdx.y;   // r-block 0..187
    const int t = threadIdx.x;
    const int lr = t >> 3;
    const int lc = (t & 7) * 4;
    const int r = by * 32 + lr;
    if (r < N_PTS) {
        float4 v = *(const float4*)(feat + (long)r * DIM + bx * 32 + lc);
        tile[lr][lc + 0] = f2h(v.x); tile[lr][lc + 1] = f2h(v.y);
        tile[lr][lc + 2] = f2h(v.z); tile[lr][lc + 3] = f2h(v.w);
    } else {
        tile[lr][lc + 0] = 0; tile[lr][lc + 1] = 0;
        tile[lr][lc + 2] = 0; tile[lr][lc + 3] = 0;
    }
    __syncthreads();
    const int orow = bx * 32 + lr;
    ushort4 o;
    o.x = tile[lc + 0][lr]; o.y = tile[lc + 1][lr];
    o.z = tile[lc + 2][lr]; o.w = tile[lc + 3][lr];
    *(ushort4*)(featT + (long)orow * WSTR + by * 32 + lc) = o;
}

// ---------------------------------------------------------------------------
// Greedy FPS — R4 reduction, float4 load path (R7, measured-good).
// ---------------------------------------------------------------------------
#define FPS_T 1024

__global__ __launch_bounds__(1024)
void fps_kernel(const float* __restrict__ Drec, int* __restrict__ idxout)
{
    const int t = threadIdx.x;
    const bool act = t < 750;
    float ds[8];
    if (act) {
        const float4* p = (const float4*)Drec + 2 * t;
        float4 a0 = p[0], a1 = p[1];
        ds[0] = a0.x; ds[1] = a0.y; ds[2] = a0.z; ds[3] = a0.w;
        ds[4] = a1.x; ds[5] = a1.y; ds[6] = a1.z; ds[7] = a1.w;
    } else {
#pragma unroll
        for (int j = 0; j < 8; j++) ds[j] = INFINITY;
    }
    __shared__ unsigned long long red[16];
    __shared__ int s_sel;
    if (t == 0) idxout[0] = 0;

    for (int it = 1; it < KSEL; it++) {
        float mv = ds[0]; int mi = 8 * t;
#pragma unroll
        for (int j = 1; j < 8; j++) {
            if (ds[j] < mv) { mv = ds[j]; mi = 8 * t + j; }
        }
        unsigned long long key = act
            ? (((unsigned long long)__float_as_uint(mv) << 32) | (unsigned)mi)
            : ~0ull;
#pragma unroll
        for (int o = 32; o > 0; o >>= 1) {
            unsigned long long other = __shfl_down(key, o);
            if (other < key) key = other;
        }
        if ((t & 63) == 0) red[t >> 6] = key;
        __syncthreads();
        if (t < 64) {
            unsigned long long k2 = (t < 16) ? red[t] : ~0ull;
#pragma unroll
            for (int o = 8; o > 0; o >>= 1) {
                unsigned long long other = __shfl_down(k2, o);
                if (other < k2) k2 = other;
            }
            if (t == 0) s_sel = (int)(unsigned)(k2 & 0xffffffffull);
        }
        __syncthreads();
        const int sel = s_sel;
        if (t == 0) idxout[it] = sel;
        if (act) {
            const float4* rp = (const float4*)(Drec + (long)sel * N_PTS) + 2 * t;
            float4 r0 = rp[0], r1 = rp[1];
            ds[0] += r0.x; ds[1] += r0.y; ds[2] += r0.z; ds[3] += r0.w;
            ds[4] += r1.x; ds[5] += r1.y; ds[6] += r1.z; ds[7] += r1.w;
        }
    }
}

__global__ __launch_bounds__(256)
void gatherb_kernel(const unsigned short* __restrict__ X, const int* __restrict__ idx,
                    unsigned short* __restrict__ roi)
{
    const int k = blockIdx.x, t = threadIdx.x;
    const unsigned short* src = X + (long)idx[k] * XSTR;   // hi part
    *(ushort4*)(roi + (long)k * DIM + t * 4) = *(const ushort4*)(src + t * 4);
}

// ---------------------------------------------------------------------------
// Gate + logit: one thread per (k,n); sin/cos computed ONCE per (k,n) and
// shared across all 16 groups (R10's fused kernel recomputed them 16x).
// Accumulation order for aw[g] identical to R10 (p,f outer, g inner) ->
// logits bit-identical. W row g gets: aff + log(relu(gate)+1e-6), in place.
// ---------------------------------------------------------------------------
__global__ __launch_bounds__(256)
void gatelogit_kernel(const float* __restrict__ bboxes,
                      const int* __restrict__ idx,
                      const float* __restrict__ Wg,
                      const float* __restrict__ bgp,
                      float* __restrict__ W)
{
    __shared__ float swg[GG][64];
    __shared__ float sbg[GG];
    __shared__ float sbb[4];
    const int t = threadIdx.x;
    const int k = blockIdx.y;
    const int n = blockIdx.x * 256 + t;
    for (int i = t; i < GG * 64; i += 256) swg[i >> 6][i & 63] = Wg[i];
    if (t < GG) sbg[t] = bgp[t];
    if (t < 4)  sbb[t] = bboxes[(long)idx[k] * 4 + t];
    __syncthreads();
    if (n >= N_PTS) return;

    const float x1 = sbb[0], y1 = sbb[1], x2 = sbb[2], y2 = sbb[3];
    const float w  = x2 - x1 + 1.f, h = y2 - y1 + 1.f;
    const float cx = 0.5f * (x1 + x2), cy = 0.5f * (y1 + y2);
    float4 rb = *(const float4*)(bboxes + (long)n * 4);
    const float wr = rb.z - rb.x + 1.f, hr = rb.w - rb.y + 1.f;
    const float cxr = 0.5f * (rb.x + rb.z), cyr = 0.5f * (rb.y + rb.w);

    float pos[4];
    pos[0] = __logf(fabsf((cx - cxr) / w) + 1e-3f);
    pos[1] = __logf(fabsf((cy - cyr) / h) + 1e-3f);
    pos[2] = __logf(w / wr);
    pos[3] = __logf(h / hr);

    const float rdm[8] = { 100.0f, 42.169650342858226f, 17.782794100389228f,
                           7.498942093324559f, 3.1622776601683795f,
                           1.333521432163324f, 0.5623413251903491f,
                           0.23713737056616552f };
    float aw[GG];
#pragma unroll
    for (int g = 0; g < GG; g++) aw[g] = sbg[g];
#pragma unroll
    for (int p = 0; p < 4; p++) {
#pragma unroll
        for (int f = 0; f < 8; f++) {
            const float arg = pos[p] * rdm[f];
            const float s_ = __sinf(arg), c_ = __cosf(arg);
            const int e = p * 16 + f;
#pragma unroll
            for (int g = 0; g < GG; g++)
                aw[g] += swg[g][e] * s_ + swg[g][e + 8] * c_;
        }
    }
    float* base = W + ((long)k * GG) * WSTR + n;
#pragma unroll
    for (int g = 0; g < GG; g++) {
        const float lg = __logf(fmaxf(aw[g], 0.f) + 1e-6f);
        base[(long)g * WSTR] += lg;
    }
}

// ---------------------------------------------------------------------------
// Softmax over n, one block per (k,g) row; row overwritten in place as f16
// (stride WSTR*2 shorts), cols 6000..6015 zeroed.
// ---------------------------------------------------------------------------
__global__ __launch_bounds__(256)
void softmax16_kernel(float* __restrict__ W)
{
    __shared__ float lg[WSTR];
    __shared__ float sred[4];
    __shared__ float sMS;
    const int t = threadIdx.x;
    float* rowp = W + (long)blockIdx.x * WSTR;

    float m = -INFINITY;
    for (int n = t; n < N_PTS; n += 256) {
        const float v = rowp[n];
        lg[n] = v;
        m = fmaxf(m, v);
    }
#pragma unroll
    for (int o = 32; o > 0; o >>= 1) m = fmaxf(m, __shfl_down(m, o));
    if ((t & 63) == 0) sred[t >> 6] = m;
    __syncthreads();
    if (t == 0) sMS = fmaxf(fmaxf(sred[0], sred[1]), fmaxf(sred[2], sred[3]));
    __syncthreads();
    m = sMS;
    __syncthreads();

    float s = 0.f;
    for (int n = t; n < N_PTS; n += 256) {
        const float e = __expf(lg[n] - m);
        lg[n] = e;
        s += e;
    }
#pragma unroll
    for (int o = 32; o > 0; o >>= 1) s += __shfl_down(s, o);
    if ((t & 63) == 0) sred[t >> 6] = s;
    __syncthreads();
    if (t == 0) sMS = sred[0] + sred[1] + sred[2] + sred[3];
    __syncthreads();
    const float inv = 1.0f / sMS;
    __syncthreads();

    unsigned short* orow = (unsigned short*)rowp;
    for (int n = t; n < WSTR; n += 256)
        orow[n] = (n < N_PTS) ? f2h(lg[n] * inv) : (unsigned short)0;
}

// ---------------------------------------------------------------------------
extern "C" void kernel_launch(void* const* d_in, const int* in_sizes, int n_in,
                              void* d_out, int out_size, void* d_ws, size_t ws_size,
                              hipStream_t stream)
{
    const float* feat   = (const float*)d_in[0];
    const float* bboxes = (const float*)d_in[1];
    const float* Wq     = (const float*)d_in[2];
    const float* bq     = (const float*)d_in[3];
    const float* Wk     = (const float*)d_in[4];
    const float* bk     = (const float*)d_in[5];
    const float* Wg     = (const float*)d_in[6];
    const float* bg     = (const float*)d_in[7];
    const float* Wv     = (const float*)d_in[8];
    const float* bv     = (const float*)d_in[9];
    float* out = (float*)d_out;
    float* ws  = (float*)d_ws;

    // ws layout (float offsets), peak ~185.1 MB (same bound as R10):
    //  [0 .. 36,000,000)  drec 6000x6000. Dead after FPS; then reused:
    //      W     [0, 28,876,800)            4800 x 6016 logits (fp32 -> f16 in place)
    //      kk_h  [28,900,000, 31,972,000)   6000x1024 f16
    //      q_h   [31,972,000, 32,125,600)   300x1024 f16
    //      roi_h [32,125,600, 32,279,200)   300x1024 f16
    //      featT [32,300,000, 35,380,192)   1024x6016 f16 (written post-FPS)
    //  [36,000,000 .. 42,144,000)  X=[hi|lo] 6000x2048 f16
    //      -> outt fp32 4800x1024 reuses [36,000,000, 40,915,200) after kk/gather
    //  [45,216,000 .. 45,740,288)  Wq_h
    //  [45,740,288 .. 46,264,576)  Wk_h
    //  [46,264,576 .. 46,270,576)  sqn
    //  [46,270,576 .. )            idx (300 ints)
    float* drec = ws;
    float* W    = ws;
    unsigned short* kk_h  = (unsigned short*)(ws + 28900000);
    unsigned short* q_h   = (unsigned short*)(ws + 31972000);
    unsigned short* roi_h = (unsigned short*)(ws + 32125600);
    unsigned short* featT = (unsigned short*)(ws + 32300000);
    unsigned short* X     = (unsigned short*)(ws + 36000000);
    float* outt           = ws + 36000000;
    unsigned short* Wq_h  = (unsigned short*)(ws + 45216000);
    unsigned short* Wk_h  = (unsigned short*)(ws + 45740288);
    float* sqnbuf         = ws + 46264576;
    int*   idxbuf         = (int*)(ws + 46270576);
    if (ws_size < (size_t)185100000) return;

    sqnpack2_kernel<<<N_PTS, 256, 0, stream>>>(feat, X, sqnbuf);
    wconv2_kernel<<<2048, 256, 0, stream>>>(Wq, Wk, Wq_h, Wk_h);

    // Gram: 2-way f16 split, 3 chunk passes (K=3072), triangular grid
    mfma_gemm<true, false><<<1128, 256, 0, stream>>>(
        X, XSTR, 0, X, XSTR, 0, drec, N_PTS, 0,
        N_PTS, N_PTS, 3072, nullptr, 0, 1.f, sqnbuf, 47);

    fps_kernel<<<1, FPS_T, 0, stream>>>(drec, idxbuf);

    // featT goes into dead drec space -> must run after FPS
    transpose_kernel<<<dim3(32, 188), 256, 0, stream>>>(feat, featT);
    gatherb_kernel<<<KSEL, 256, 0, stream>>>(X, idxbuf, roi_h);

    // q = roi @ Wq^T + bq  (f16 out)
    mfma_gemm<false, true><<<dim3(8, 3, 1), 256, 0, stream>>>(
        roi_h, 1024, 0, Wq_h, 1024, 0, q_h, 1024, 0,
        KSEL, DIM, DIM, bq, 0, 1.f, nullptr, 0);
    // kk = feat @ Wk^T + bk  (f16 out; A = hi part of X, lda XSTR)
    mfma_gemm<false, true><<<dim3(8, 47, 1), 256, 0, stream>>>(
        X, XSTR, 0, Wk_h, 1024, 0, kk_h, 1024, 0,
        N_PTS, DIM, DIM, bk, 0, 1.f, nullptr, 0);

    // aff = (q . kk^T)/8 per group -> W fp32  (batched z=16, K=64)
    mfma_gemm<false, false><<<dim3(47, 3, GG), 256, 0, stream>>>(
        q_h, 1024, 64, kk_h, 1024, 64, W, (long)GG * WSTR, WSTR,
        KSEL, N_PTS, 64, nullptr, 0, 0.125f, nullptr, 0);

    // gate + logit (sin/cos once per (k,n), shared across 16 groups)
    gatelogit_kernel<<<dim3(24, KSEL), 256, 0, stream>>>(
        bboxes, idxbuf, Wg, bg, W);
    // softmax per (k,g) row; W rows become f16 probs in place
    softmax16_kernel<<<KSEL * GG, 256, 0, stream>>>(W);

    // out_t = P @ feat  (A = f16 probs in place, lda 2*WSTR shorts; B = featT)
    mfma_gemm<false, false><<<dim3(8, 38, 1), 256, 0, stream>>>(
        (unsigned short*)W, 2 * WSTR, 0, featT, WSTR, 0, outt, DIM, 0,
        KSEL * GG, DIM, WSTR, nullptr, 0, 1.f, nullptr, 0);

    // out = out_t . Wv + bv (fp32, small)
    sgemm_kernel<true><<<dim3(1, 3, GG), 256, 0, stream>>>(
        outt, (long)GG * DIM, DIM, Wv, DIM, (long)DGR * DIM, out, DIM, DGR,
        KSEL, DGR, DIM, bv, DGR, 1.f);
}

// Round 12
// 1211.303 us; speedup vs baseline: 1.3670x; 1.0129x over previous
//
#include <hip/hip_runtime.h>
#include <math.h>

#define N_PTS 6000
#define DIM   1024
#define KSEL  300
#define GG    16
#define DGR   64
#define WSTR  6016   // padded row stride for logits W (6000 -> 6016)
#define XSTR  2048   // X = [hi|lo] f16 2-way split, row stride

typedef _Float16 half8 __attribute__((ext_vector_type(8)));
typedef float floatx4 __attribute__((ext_vector_type(4)));

__device__ __forceinline__ unsigned short f2h(float x) {
    _Float16 h = (_Float16)x;                   // v_cvt_f16_f32, RNE
    return __builtin_bit_cast(unsigned short, h);
}
__device__ __forceinline__ float h2f(unsigned short u) {
    return (float)__builtin_bit_cast(_Float16, u);
}

__device__ __forceinline__ void async_copy16(const void* gsrc, void* ldst) {
    __builtin_amdgcn_global_load_lds(
        (const __attribute__((address_space(1))) void*)gsrc,
        (__attribute__((address_space(3))) void*)ldst,
        16, 0, 0);
}

// ---------------------------------------------------------------------------
// MFMA f16 GEMM, NT: C[i][j] = scale * sum_k A[i,k]*B[j,k] (+bias[j])
// 128x128 tile, BK=32, 256 threads (4 waves, each 64x64 = 4x4 16x16 tiles).
// GRAM: A=B=X=[hi|lo] f16 (lda 2048); 3 chunk passes (hi.hi + hi.lo + lo.hi
//       == x.y to ~fp32 accuracy); triangular grid, 1/cdist epilogue +
//       mirrored store (R7 epilogue — NT and LDS variants both regressed).
// OF16: store output as f16 (for q feeding the aff MFMA).
// ---------------------------------------------------------------------------
template<bool GRAM, bool OF16>
__global__ __launch_bounds__(256)
void mfma_gemm(const void* Av, long lda, long az,
               const void* Bv, long ldb, long bz,
               void* Cv, long ldc, long cz,
               int M, int N, int Kd,
               const float* __restrict__ bias, long biasz,
               float scale, const float* __restrict__ sqn, int nbm)
{
    __shared__ unsigned short As[128 * 32];
    __shared__ unsigned short Bs[128 * 32];
    const int t = threadIdx.x;
    const int w = t >> 6, l = t & 63;
    const int wr = w >> 1, wc = w & 1;

    int row0, col0, bi = 0, bj = 0;
    if (GRAM) {
        int tt = blockIdx.x, rem = nbm;
        while (tt >= rem) { tt -= rem; bi++; rem--; }
        bj = bi + tt;
        row0 = bi * 128; col0 = bj * 128;
    } else {
        row0 = blockIdx.y * 128; col0 = blockIdx.x * 128;
    }
    const int z = blockIdx.z;
    const unsigned short* Ab = (const unsigned short*)Av + (long)z * az;
    const unsigned short* Bb = (const unsigned short*)Bv + (long)z * bz;

    floatx4 acc[4][4];
#pragma unroll
    for (int i = 0; i < 4; i++)
#pragma unroll
        for (int j = 0; j < 4; j++) acc[i][j] = (floatx4){0.f, 0.f, 0.f, 0.f};

    // clamped staging row indices (hoisted out of the K loop)
    int ra0 = row0 + (w * 2 + 0) * 16 + (l >> 2); ra0 = ra0 < M ? ra0 : M - 1;
    int ra1 = row0 + (w * 2 + 1) * 16 + (l >> 2); ra1 = ra1 < M ? ra1 : M - 1;
    int rb0 = col0 + (w * 2 + 0) * 16 + (l >> 2); rb0 = rb0 < N ? rb0 : N - 1;
    int rb1 = col0 + (w * 2 + 1) * 16 + (l >> 2); rb1 = rb1 < N ? rb1 : N - 1;
    const long lane_off = (l & 3) * 8;
    const unsigned short* gA0 = Ab + (long)ra0 * lda + lane_off;
    const unsigned short* gA1 = Ab + (long)ra1 * lda + lane_off;
    const unsigned short* gB0 = Bb + (long)rb0 * ldb + lane_off;
    const unsigned short* gB1 = Bb + (long)rb1 * ldb + lane_off;
    unsigned short* lA0 = As + ((w * 2 + 0) * 16) * 32;
    unsigned short* lA1 = As + ((w * 2 + 1) * 16) * 32;
    unsigned short* lB0 = Bs + ((w * 2 + 0) * 16) * 32;
    unsigned short* lB1 = Bs + ((w * 2 + 1) * 16) * 32;

    auto kstep = [&](long offA, long offB) {
        async_copy16(gA0 + offA, (void*)lA0);
        async_copy16(gA1 + offA, (void*)lA1);
        async_copy16(gB0 + offB, (void*)lB0);
        async_copy16(gB1 + offB, (void*)lB1);
        __syncthreads();
        half8 af[4], bfr[4];
#pragma unroll
        for (int ti = 0; ti < 4; ti++)
            af[ti] = *(const half8*)(As + (wr * 64 + ti * 16 + (l & 15)) * 32 + (l >> 4) * 8);
#pragma unroll
        for (int tj = 0; tj < 4; tj++)
            bfr[tj] = *(const half8*)(Bs + (wc * 64 + tj * 16 + (l & 15)) * 32 + (l >> 4) * 8);
#pragma unroll
        for (int ti = 0; ti < 4; ti++)
#pragma unroll
            for (int tj = 0; tj < 4; tj++)
                acc[ti][tj] = __builtin_amdgcn_mfma_f32_16x16x32_f16(
                    af[ti], bfr[tj], acc[ti][tj], 0, 0, 0);
        __syncthreads();
    };

    if (GRAM) {
        // 3 chunk passes, compile-time part offsets (hi=0, lo=1024)
#pragma unroll 1
        for (int k0 = 0; k0 < 1024; k0 += 32) kstep(k0, k0);              // hi.hi
#pragma unroll 1
        for (int k0 = 0; k0 < 1024; k0 += 32) kstep(k0, k0 + 1024);      // hi.lo
#pragma unroll 1
        for (int k0 = 0; k0 < 1024; k0 += 32) kstep(k0 + 1024, k0);      // lo.hi
    } else {
#pragma unroll 1
        for (int k0 = 0; k0 < Kd; k0 += 32) kstep(k0, k0);
    }

    float* Cf = (float*)Cv + (long)z * cz;
    unsigned short* Ch = (unsigned short*)Cv + (long)z * cz;
    const float* bias_p = bias ? bias + (long)z * biasz : nullptr;
#pragma unroll
    for (int ti = 0; ti < 4; ti++) {
#pragma unroll
        for (int tj = 0; tj < 4; tj++) {
            const int c = col0 + wc * 64 + tj * 16 + (l & 15);
            const int rb = row0 + wr * 64 + ti * 16 + (l >> 4) * 4;
            if (GRAM) {
                float rec4[4];
#pragma unroll
                for (int reg = 0; reg < 4; reg++) {
                    int r = rb + reg;
                    if (r >= M || c >= N) { rec4[reg] = 0.f; continue; }
                    if (r == c) { rec4[reg] = INFINITY; }
                    else {
                        float sq = sqn[r] + sqn[c] - 2.f * acc[ti][tj][reg];
                        rec4[reg] = 1.0f / sqrtf(fmaxf(sq, 0.f));
                    }
                    Cf[(long)r * ldc + c] = rec4[reg];
                }
                if (bi != bj && c < N && rb + 3 < M) {  // mirrored float4 store
                    *(float4*)(Cf + (long)c * ldc + rb) =
                        make_float4(rec4[0], rec4[1], rec4[2], rec4[3]);
                }
            } else {
#pragma unroll
                for (int reg = 0; reg < 4; reg++) {
                    int r = rb + reg;
                    if (r >= M || c >= N) continue;
                    float v = acc[ti][tj][reg] * scale;
                    if (bias_p) v += bias_p[c];
                    if (OF16) Ch[(long)r * ldc + c] = f2h(v);
                    else      Cf[(long)r * ldc + c] = v;
                }
            }
        }
    }
}

// ---------------------------------------------------------------------------
// FAT KERNEL: block 0 = greedy FPS (R7/R11 code, byte-identical selections);
// blocks 1..96 = kk GEMM (feat @ Wk^T + bk, f16 out), four M-stacked 128x128
// tiles per 1024-thread block (per-sub As, SHARED Bs). kk is idx-independent,
// so it rides in fps's 347us shadow on the otherwise-idle 255 CUs.
// ---------------------------------------------------------------------------
#define FPS_T 1024

__global__ __launch_bounds__(1024)
void fps_kk_kernel(const float* __restrict__ Drec, int* __restrict__ idxout,
                   const unsigned short* __restrict__ X,
                   const unsigned short* __restrict__ Wk_h,
                   const float* __restrict__ bk,
                   unsigned short* __restrict__ kk_h)
{
    __shared__ unsigned long long red[16];
    __shared__ int s_sel;
    __shared__ unsigned short As[4][128 * 32];
    __shared__ unsigned short Bs[128 * 32];
    const int t = threadIdx.x;

    if (blockIdx.x == 0) {
        // ---------------- FPS (frozen: R4 reduction + R7 float4 loads) -----
        const bool act = t < 750;
        float ds[8];
        if (act) {
            const float4* p = (const float4*)Drec + 2 * t;
            float4 a0 = p[0], a1 = p[1];
            ds[0] = a0.x; ds[1] = a0.y; ds[2] = a0.z; ds[3] = a0.w;
            ds[4] = a1.x; ds[5] = a1.y; ds[6] = a1.z; ds[7] = a1.w;
        } else {
#pragma unroll
            for (int j = 0; j < 8; j++) ds[j] = INFINITY;
        }
        if (t == 0) idxout[0] = 0;

        for (int it = 1; it < KSEL; it++) {
            float mv = ds[0]; int mi = 8 * t;
#pragma unroll
            for (int j = 1; j < 8; j++) {
                if (ds[j] < mv) { mv = ds[j]; mi = 8 * t + j; }
            }
            unsigned long long key = act
                ? (((unsigned long long)__float_as_uint(mv) << 32) | (unsigned)mi)
                : ~0ull;
#pragma unroll
            for (int o = 32; o > 0; o >>= 1) {
                unsigned long long other = __shfl_down(key, o);
                if (other < key) key = other;
            }
            if ((t & 63) == 0) red[t >> 6] = key;
            __syncthreads();
            if (t < 64) {
                unsigned long long k2 = (t < 16) ? red[t] : ~0ull;
#pragma unroll
                for (int o = 8; o > 0; o >>= 1) {
                    unsigned long long other = __shfl_down(k2, o);
                    if (other < k2) k2 = other;
                }
                if (t == 0) s_sel = (int)(unsigned)(k2 & 0xffffffffull);
            }
            __syncthreads();
            const int sel = s_sel;
            if (t == 0) idxout[it] = sel;
            if (act) {
                const float4* rp = (const float4*)(Drec + (long)sel * N_PTS) + 2 * t;
                float4 r0 = rp[0], r1 = rp[1];
                ds[0] += r0.x; ds[1] += r0.y; ds[2] += r0.z; ds[3] += r0.w;
                ds[4] += r1.x; ds[5] += r1.y; ds[6] += r1.z; ds[7] += r1.w;
            }
        }
        return;
    }

    // ---------------- kk GEMM: 4 stacked 128x128 tiles ---------------------
    const int b = blockIdx.x - 1;     // 0..95
    const int mg = b >> 3;            // M group (4 tiles of 128 rows)
    const int nt = b & 7;             // N tile
    const int w = t >> 6, l = t & 63;
    const int sub = w >> 2;           // 0..3: which M tile
    const int wsu = w & 3;            // wave within sub-block
    const int wr = wsu >> 1, wc = wsu & 1;
    const int row0 = (mg * 4 + sub) * 128;
    const int col0 = nt * 128;

    floatx4 acc[4][4];
#pragma unroll
    for (int i = 0; i < 4; i++)
#pragma unroll
        for (int j = 0; j < 4; j++) acc[i][j] = (floatx4){0.f, 0.f, 0.f, 0.f};

    int ra0 = row0 + (wsu * 2 + 0) * 16 + (l >> 2); ra0 = ra0 < N_PTS ? ra0 : N_PTS - 1;
    int ra1 = row0 + (wsu * 2 + 1) * 16 + (l >> 2); ra1 = ra1 < N_PTS ? ra1 : N_PTS - 1;
    const long lane_off = (l & 3) * 8;
    const unsigned short* gA0 = X + (long)ra0 * XSTR + lane_off;
    const unsigned short* gA1 = X + (long)ra1 * XSTR + lane_off;
    unsigned short* lA0 = As[sub] + ((wsu * 2 + 0) * 16) * 32;
    unsigned short* lA1 = As[sub] + ((wsu * 2 + 1) * 16) * 32;
    const int rb0 = col0 + (wsu * 2 + 0) * 16 + (l >> 2);   // < 1024 always
    const int rb1 = col0 + (wsu * 2 + 1) * 16 + (l >> 2);
    const unsigned short* gB0 = Wk_h + (long)rb0 * DIM + lane_off;
    const unsigned short* gB1 = Wk_h + (long)rb1 * DIM + lane_off;
    unsigned short* lB0 = Bs + ((wsu * 2 + 0) * 16) * 32;
    unsigned short* lB1 = Bs + ((wsu * 2 + 1) * 16) * 32;

#pragma unroll 1
    for (int k0 = 0; k0 < DIM; k0 += 32) {
        async_copy16(gA0 + k0, (void*)lA0);
        async_copy16(gA1 + k0, (void*)lA1);
        if (sub == 0) {
            async_copy16(gB0 + k0, (void*)lB0);
            async_copy16(gB1 + k0, (void*)lB1);
        }
        __syncthreads();
        half8 af[4], bfr[4];
#pragma unroll
        for (int ti = 0; ti < 4; ti++)
            af[ti] = *(const half8*)(As[sub] + (wr * 64 + ti * 16 + (l & 15)) * 32 + (l >> 4) * 8);
#pragma unroll
        for (int tj = 0; tj < 4; tj++)
            bfr[tj] = *(const half8*)(Bs + (wc * 64 + tj * 16 + (l & 15)) * 32 + (l >> 4) * 8);
#pragma unroll
        for (int ti = 0; ti < 4; ti++)
#pragma unroll
            for (int tj = 0; tj < 4; tj++)
                acc[ti][tj] = __builtin_amdgcn_mfma_f32_16x16x32_f16(
                    af[ti], bfr[tj], acc[ti][tj], 0, 0, 0);
        __syncthreads();
    }

#pragma unroll
    for (int ti = 0; ti < 4; ti++) {
#pragma unroll
        for (int tj = 0; tj < 4; tj++) {
            const int c = col0 + wc * 64 + tj * 16 + (l & 15);
            const int rbase = row0 + wr * 64 + ti * 16 + (l >> 4) * 4;
            const float bkc = bk[c];
#pragma unroll
            for (int reg = 0; reg < 4; reg++) {
                const int r = rbase + reg;
                if (r < N_PTS)
                    kk_h[(long)r * DIM + c] = f2h(acc[ti][tj][reg] + bkc);
            }
        }
    }
}

// ---------------------------------------------------------------------------
// fp32 SGEMM kept for the small Wv projection only.
// ---------------------------------------------------------------------------
#define BM 128
#define BN 128
#define BKK 8
#define TM 8
#define TN 8

template<bool TRANSB>
__global__ __launch_bounds__(256)
void sgemm_kernel(const float* __restrict__ A, long lda, long az,
                  const float* __restrict__ B, long ldb, long bz,
                  float* __restrict__ C, long ldc, long cz,
                  int M, int N, int Kd,
                  const float* __restrict__ bias, long biasz, float scale)
{
    __shared__ float As[BKK][BM];
    __shared__ float Bs[BKK][BN];
    const int t = threadIdx.x;
    const int z = blockIdx.z;
    A += (long)z * az; B += (long)z * bz; C += (long)z * cz;
    const float* bias_p = bias ? (bias + (long)z * biasz) : nullptr;
    const int row0 = blockIdx.y * BM;
    const int col0 = blockIdx.x * BN;
    const int tx = t & 15, ty = t >> 4;

    float acc[TM][TN];
#pragma unroll
    for (int i = 0; i < TM; i++)
#pragma unroll
        for (int j = 0; j < TN; j++) acc[i][j] = 0.f;

    const int lrow = t >> 1;
    const int lcol = (t & 1) * 4;

    for (int k0 = 0; k0 < Kd; k0 += BKK) {
        {
            int r = row0 + lrow; r = (r < M) ? r : (M - 1);
            float4 v = *(const float4*)(A + (long)r * lda + (k0 + lcol));
            As[lcol + 0][lrow] = v.x; As[lcol + 1][lrow] = v.y;
            As[lcol + 2][lrow] = v.z; As[lcol + 3][lrow] = v.w;
        }
        {
            int r = col0 + lrow; r = (r < N) ? r : (N - 1);
            float4 v = *(const float4*)(B + (long)r * ldb + (k0 + lcol));
            Bs[lcol + 0][lrow] = v.x; Bs[lcol + 1][lrow] = v.y;
            Bs[lcol + 2][lrow] = v.z; Bs[lcol + 3][lrow] = v.w;
        }
        __syncthreads();
#pragma unroll
        for (int kk = 0; kk < BKK; kk++) {
            float a[TM], b[TN];
#pragma unroll
            for (int i = 0; i < TM; i++) a[i] = As[kk][ty * TM + i];
#pragma unroll
            for (int j = 0; j < TN; j++) b[j] = Bs[kk][tx * TN + j];
#pragma unroll
            for (int i = 0; i < TM; i++)
#pragma unroll
                for (int j = 0; j < TN; j++)
                    acc[i][j] = fmaf(a[i], b[j], acc[i][j]);
        }
        __syncthreads();
    }
#pragma unroll
    for (int i = 0; i < TM; i++) {
        int r = row0 + ty * TM + i;
        if (r >= M) continue;
#pragma unroll
        for (int j = 0; j < TN; j++) {
            int c = col0 + tx * TN + j;
            if (c >= N) continue;
            float v = acc[i][j] * scale;
            if (bias_p) v += bias_p[c];
            C[(long)r * ldc + c] = v;
        }
    }
}

// ---------------------------------------------------------------------------
// Fused: sqn[r] = ||feat[r]||^2  AND  X = [hi|lo] f16 2-way split.
// ---------------------------------------------------------------------------
__global__ __launch_bounds__(256)
void sqnpack2_kernel(const float* __restrict__ feat,
                     unsigned short* __restrict__ X, float* __restrict__ sqn)
{
    const int r = blockIdx.x, t = threadIdx.x;
    float4 v = *(const float4*)(feat + (long)r * DIM + t * 4);
    float s = v.x * v.x + v.y * v.y + v.z * v.z + v.w * v.w;

    ushort4 hi, lo;
    hi.x = f2h(v.x); lo.x = f2h(v.x - h2f(hi.x));
    hi.y = f2h(v.y); lo.y = f2h(v.y - h2f(hi.y));
    hi.z = f2h(v.z); lo.z = f2h(v.z - h2f(hi.z));
    hi.w = f2h(v.w); lo.w = f2h(v.w - h2f(hi.w));
    *(ushort4*)(X + (long)r * XSTR + t * 4) = hi;
    *(ushort4*)(X + (long)r * XSTR + 1024 + t * 4) = lo;

#pragma unroll
    for (int o = 32; o > 0; o >>= 1) s += __shfl_down(s, o);
    __shared__ float sr[4];
    if ((t & 63) == 0) sr[t >> 6] = s;
    __syncthreads();
    if (t == 0) sqn[r] = sr[0] + sr[1] + sr[2] + sr[3];
}

// Both weight conversions in one launch: blocks [0,1024) -> Wq, [1024,2048) -> Wk
__global__ __launch_bounds__(256)
void wconv2_kernel(const float* __restrict__ Wq, const float* __restrict__ Wk,
                   unsigned short* __restrict__ Wq_h, unsigned short* __restrict__ Wk_h)
{
    const int b = blockIdx.x;
    const float* src = (b < 1024) ? Wq : Wk;
    unsigned short* dst = (b < 1024) ? Wq_h : Wk_h;
    const long i = ((long)(b & 1023) * 256 + threadIdx.x) * 4;
    float4 v = *(const float4*)(src + i);
    ushort4 o;
    o.x = f2h(v.x); o.y = f2h(v.y); o.z = f2h(v.z); o.w = f2h(v.w);
    *(ushort4*)(dst + i) = o;
}

// featT[d][r] = f16(feat[r][d]), 1024 x 6016 (cols 6000..6015 zero)
__global__ __launch_bounds__(256)
void transpose_kernel(const float* __restrict__ feat, unsigned short* __restrict__ featT)
{
    __shared__ unsigned short tile[32][33];
    const int bx = blockIdx.x;   // d-block 0..31
    const int by = blockIdx.y;   // r-block 0..187
    const int t = threadIdx.x;
    const int lr = t >> 3;
    const int lc = (t & 7) * 4;
    const int r = by * 32 + lr;
    if (r < N_PTS) {
        float4 v = *(const float4*)(feat + (long)r * DIM + bx * 32 + lc);
        tile[lr][lc + 0] = f2h(v.x); tile[lr][lc + 1] = f2h(v.y);
        tile[lr][lc + 2] = f2h(v.z); tile[lr][lc + 3] = f2h(v.w);
    } else {
        tile[lr][lc + 0] = 0; tile[lr][lc + 1] = 0;
        tile[lr][lc + 2] = 0; tile[lr][lc + 3] = 0;
    }
    __syncthreads();
    const int orow = bx * 32 + lr;
    ushort4 o;
    o.x = tile[lc + 0][lr]; o.y = tile[lc + 1][lr];
    o.z = tile[lc + 2][lr]; o.w = tile[lc + 3][lr];
    *(ushort4*)(featT + (long)orow * WSTR + by * 32 + lc) = o;
}

__global__ __launch_bounds__(256)
void gatherb_kernel(const unsigned short* __restrict__ X, const int* __restrict__ idx,
                    unsigned short* __restrict__ roi)
{
    const int k = blockIdx.x, t = threadIdx.x;
    const unsigned short* src = X + (long)idx[k] * XSTR;   // hi part
    *(ushort4*)(roi + (long)k * DIM + t * 4) = *(const ushort4*)(src + t * 4);
}

// ---------------------------------------------------------------------------
// Gate + logit: one thread per (k,n); sin/cos computed ONCE per (k,n) and
// shared across all 16 groups. Accumulation order (p,f outer, g inner).
// ---------------------------------------------------------------------------
__global__ __launch_bounds__(256)
void gatelogit_kernel(const float* __restrict__ bboxes,
                      const int* __restrict__ idx,
                      const float* __restrict__ Wg,
                      const float* __restrict__ bgp,
                      float* __restrict__ W)
{
    __shared__ float swg[GG][64];
    __shared__ float sbg[GG];
    __shared__ float sbb[4];
    const int t = threadIdx.x;
    const int k = blockIdx.y;
    const int n = blockIdx.x * 256 + t;
    for (int i = t; i < GG * 64; i += 256) swg[i >> 6][i & 63] = Wg[i];
    if (t < GG) sbg[t] = bgp[t];
    if (t < 4)  sbb[t] = bboxes[(long)idx[k] * 4 + t];
    __syncthreads();
    if (n >= N_PTS) return;

    const float x1 = sbb[0], y1 = sbb[1], x2 = sbb[2], y2 = sbb[3];
    const float w  = x2 - x1 + 1.f, h = y2 - y1 + 1.f;
    const float cx = 0.5f * (x1 + x2), cy = 0.5f * (y1 + y2);
    float4 rb = *(const float4*)(bboxes + (long)n * 4);
    const float wr = rb.z - rb.x + 1.f, hr = rb.w - rb.y + 1.f;
    const float cxr = 0.5f * (rb.x + rb.z), cyr = 0.5f * (rb.y + rb.w);

    float pos[4];
    pos[0] = __logf(fabsf((cx - cxr) / w) + 1e-3f);
    pos[1] = __logf(fabsf((cy - cyr) / h) + 1e-3f);
    pos[2] = __logf(w / wr);
    pos[3] = __logf(h / hr);

    const float rdm[8] = { 100.0f, 42.169650342858226f, 17.782794100389228f,
                           7.498942093324559f, 3.1622776601683795f,
                           1.333521432163324f, 0.5623413251903491f,
                           0.23713737056616552f };
    float aw[GG];
#pragma unroll
    for (int g = 0; g < GG; g++) aw[g] = sbg[g];
#pragma unroll
    for (int p = 0; p < 4; p++) {
#pragma unroll
        for (int f = 0; f < 8; f++) {
            const float arg = pos[p] * rdm[f];
            const float s_ = __sinf(arg), c_ = __cosf(arg);
            const int e = p * 16 + f;
#pragma unroll
            for (int g = 0; g < GG; g++)
                aw[g] += swg[g][e] * s_ + swg[g][e + 8] * c_;
        }
    }
    float* base = W + ((long)k * GG) * WSTR + n;
#pragma unroll
    for (int g = 0; g < GG; g++) {
        const float lg = __logf(fmaxf(aw[g], 0.f) + 1e-6f);
        base[(long)g * WSTR] += lg;
    }
}

// ---------------------------------------------------------------------------
// Softmax over n, one block per (k,g) row; row overwritten in place as f16
// (stride WSTR*2 shorts), cols 6000..6015 zeroed.
// ---------------------------------------------------------------------------
__global__ __launch_bounds__(256)
void softmax16_kernel(float* __restrict__ W)
{
    __shared__ float lg[WSTR];
    __shared__ float sred[4];
    __shared__ float sMS;
    const int t = threadIdx.x;
    float* rowp = W + (long)blockIdx.x * WSTR;

    float m = -INFINITY;
    for (int n = t; n < N_PTS; n += 256) {
        const float v = rowp[n];
        lg[n] = v;
        m = fmaxf(m, v);
    }
#pragma unroll
    for (int o = 32; o > 0; o >>= 1) m = fmaxf(m, __shfl_down(m, o));
    if ((t & 63) == 0) sred[t >> 6] = m;
    __syncthreads();
    if (t == 0) sMS = fmaxf(fmaxf(sred[0], sred[1]), fmaxf(sred[2], sred[3]));
    __syncthreads();
    m = sMS;
    __syncthreads();

    float s = 0.f;
    for (int n = t; n < N_PTS; n += 256) {
        const float e = __expf(lg[n] - m);
        lg[n] = e;
        s += e;
    }
#pragma unroll
    for (int o = 32; o > 0; o >>= 1) s += __shfl_down(s, o);
    if ((t & 63) == 0) sred[t >> 6] = s;
    __syncthreads();
    if (t == 0) sMS = sred[0] + sred[1] + sred[2] + sred[3];
    __syncthreads();
    const float inv = 1.0f / sMS;
    __syncthreads();

    unsigned short* orow = (unsigned short*)rowp;
    for (int n = t; n < WSTR; n += 256)
        orow[n] = (n < N_PTS) ? f2h(lg[n] * inv) : (unsigned short)0;
}

// ---------------------------------------------------------------------------
extern "C" void kernel_launch(void* const* d_in, const int* in_sizes, int n_in,
                              void* d_out, int out_size, void* d_ws, size_t ws_size,
                              hipStream_t stream)
{
    const float* feat   = (const float*)d_in[0];
    const float* bboxes = (const float*)d_in[1];
    const float* Wq     = (const float*)d_in[2];
    const float* bq     = (const float*)d_in[3];
    const float* Wk     = (const float*)d_in[4];
    const float* bk     = (const float*)d_in[5];
    const float* Wg     = (const float*)d_in[6];
    const float* bg     = (const float*)d_in[7];
    const float* Wv     = (const float*)d_in[8];
    const float* bv     = (const float*)d_in[9];
    float* out = (float*)d_out;
    float* ws  = (float*)d_ws;

    // ws layout (float offsets), peak ~185.1 MB (<= 190.7 MB known-safe):
    //  [0 .. 36,000,000)  drec 6000x6000. Dead after FPS; then reused:
    //      W     [0, 28,876,800)            4800 x 6016 logits (fp32 -> f16 in place)
    //      q_h   [31,972,000, 32,125,600)   300x1024 f16
    //      roi_h [32,125,600, 32,279,200)   300x1024 f16
    //      featT [32,300,000, 35,380,192)   1024x6016 f16 (written post-FPS)
    //  [36,000,000 .. 42,144,000)  X=[hi|lo] 6000x2048 f16
    //      -> outt fp32 4800x1024 reuses [36,000,000, 40,915,200) after kk/gather
    //  [42,144,000 .. 45,216,000)  kk_h 6000x1024 f16  (written DURING fps
    //                              by the fat kernel -> outside drec!)
    //  [45,216,000 .. 45,740,288)  Wq_h
    //  [45,740,288 .. 46,264,576)  Wk_h
    //  [46,264,576 .. 46,270,576)  sqn
    //  [46,270,576 .. )            idx (300 ints)
    float* drec = ws;
    float* W    = ws;
    unsigned short* q_h   = (unsigned short*)(ws + 31972000);
    unsigned short* roi_h = (unsigned short*)(ws + 32125600);
    unsigned short* featT = (unsigned short*)(ws + 32300000);
    unsigned short* X     = (unsigned short*)(ws + 36000000);
    float* outt           = ws + 36000000;
    unsigned short* kk_h  = (unsigned short*)(ws + 42144000);
    unsigned short* Wq_h  = (unsigned short*)(ws + 45216000);
    unsigned short* Wk_h  = (unsigned short*)(ws + 45740288);
    float* sqnbuf         = ws + 46264576;
    int*   idxbuf         = (int*)(ws + 46270576);
    if (ws_size < (size_t)185100000) return;

    sqnpack2_kernel<<<N_PTS, 256, 0, stream>>>(feat, X, sqnbuf);
    wconv2_kernel<<<2048, 256, 0, stream>>>(Wq, Wk, Wq_h, Wk_h);

    // Gram: 2-way f16 split, 3 chunk passes (K=3072), triangular grid
    mfma_gemm<true, false><<<1128, 256, 0, stream>>>(
        X, XSTR, 0, X, XSTR, 0, drec, N_PTS, 0,
        N_PTS, N_PTS, 3072, nullptr, 0, 1.f, sqnbuf, 47);

    // FAT: block 0 = fps; blocks 1..96 = kk GEMM hidden in fps's shadow
    fps_kk_kernel<<<97, 1024, 0, stream>>>(drec, idxbuf, X, Wk_h, bk, kk_h);

    // featT goes into dead drec space -> must run after FPS
    transpose_kernel<<<dim3(32, 188), 256, 0, stream>>>(feat, featT);
    gatherb_kernel<<<KSEL, 256, 0, stream>>>(X, idxbuf, roi_h);

    // q = roi @ Wq^T + bq  (f16 out)
    mfma_gemm<false, true><<<dim3(8, 3, 1), 256, 0, stream>>>(
        roi_h, 1024, 0, Wq_h, 1024, 0, q_h, 1024, 0,
        KSEL, DIM, DIM, bq, 0, 1.f, nullptr, 0);

    // aff = (q . kk^T)/8 per group -> W fp32  (batched z=16, K=64)
    mfma_gemm<false, false><<<dim3(47, 3, GG), 256, 0, stream>>>(
        q_h, 1024, 64, kk_h, 1024, 64, W, (long)GG * WSTR, WSTR,
        KSEL, N_PTS, 64, nullptr, 0, 0.125f, nullptr, 0);

    // gate + logit (sin/cos once per (k,n), shared across 16 groups)
    gatelogit_kernel<<<dim3(24, KSEL), 256, 0, stream>>>(
        bboxes, idxbuf, Wg, bg, W);
    // softmax per (k,g) row; W rows become f16 probs in place
    softmax16_kernel<<<KSEL * GG, 256, 0, stream>>>(W);

    // out_t = P @ feat  (A = f16 probs in place, lda 2*WSTR shorts; B = featT)
    mfma_gemm<false, false><<<dim3(8, 38, 1), 256, 0, stream>>>(
        (unsigned short*)W, 2 * WSTR, 0, featT, WSTR, 0, outt, DIM, 0,
        KSEL * GG, DIM, WSTR, nullptr, 0, 1.f, nullptr, 0);

    // out = out_t . Wv + bv (fp32, small)
    sgemm_kernel<true><<<dim3(1, 3, GG), 256, 0, stream>>>(
        outt, (long)GG * DIM, DIM, Wv, DIM, (long)DGR * DIM, out, DIM, DGR,
        KSEL, DGR, DIM, bv, DGR, 1.f);
}

// Round 13
// 1102.215 us; speedup vs baseline: 1.5023x; 1.0990x over previous
//
#include <hip/hip_runtime.h>
#include <math.h>

#define N_PTS 6000
#define DIM   1024
#define KSEL  300
#define GG    16
#define DGR   64
#define WSTR  6016   // padded row stride for logits W (6000 -> 6016)
#define XSTR  2048   // X = [hi|lo] f16 2-way split, row stride

typedef _Float16 half8 __attribute__((ext_vector_type(8)));
typedef float floatx4 __attribute__((ext_vector_type(4)));

__device__ __forceinline__ unsigned short f2h(float x) {
    _Float16 h = (_Float16)x;                   // v_cvt_f16_f32, RNE
    return __builtin_bit_cast(unsigned short, h);
}
__device__ __forceinline__ float h2f(unsigned short u) {
    return (float)__builtin_bit_cast(_Float16, u);
}

__device__ __forceinline__ void async_copy16(const void* gsrc, void* ldst) {
    __builtin_amdgcn_global_load_lds(
        (const __attribute__((address_space(1))) void*)gsrc,
        (__attribute__((address_space(3))) void*)ldst,
        16, 0, 0);
}

// ---------------------------------------------------------------------------
// MFMA f16 GEMM, NT: C[i][j] = scale * sum_k A[i,k]*B[j,k] (+bias[j])
// 128x128 tile, BK=32, 256 threads. Batched over z (az/bz/cz element strides;
// az/bz double as split-K offsets for out_t).
// OF16: store output as f16.
// ---------------------------------------------------------------------------
template<bool OF16>
__global__ __launch_bounds__(256)
void mfma_gemm(const void* Av, long lda, long az,
               const void* Bv, long ldb, long bz,
               void* Cv, long ldc, long cz,
               int M, int N, int Kd,
               const float* __restrict__ bias, long biasz, float scale)
{
    __shared__ unsigned short As[128 * 32];
    __shared__ unsigned short Bs[128 * 32];
    const int t = threadIdx.x;
    const int w = t >> 6, l = t & 63;
    const int wr = w >> 1, wc = w & 1;
    const int row0 = blockIdx.y * 128, col0 = blockIdx.x * 128;
    const int z = blockIdx.z;
    const unsigned short* Ab = (const unsigned short*)Av + (long)z * az;
    const unsigned short* Bb = (const unsigned short*)Bv + (long)z * bz;

    floatx4 acc[4][4];
#pragma unroll
    for (int i = 0; i < 4; i++)
#pragma unroll
        for (int j = 0; j < 4; j++) acc[i][j] = (floatx4){0.f, 0.f, 0.f, 0.f};

    int ra0 = row0 + (w * 2 + 0) * 16 + (l >> 2); ra0 = ra0 < M ? ra0 : M - 1;
    int ra1 = row0 + (w * 2 + 1) * 16 + (l >> 2); ra1 = ra1 < M ? ra1 : M - 1;
    int rb0 = col0 + (w * 2 + 0) * 16 + (l >> 2); rb0 = rb0 < N ? rb0 : N - 1;
    int rb1 = col0 + (w * 2 + 1) * 16 + (l >> 2); rb1 = rb1 < N ? rb1 : N - 1;
    const long lane_off = (l & 3) * 8;
    const unsigned short* gA0 = Ab + (long)ra0 * lda + lane_off;
    const unsigned short* gA1 = Ab + (long)ra1 * lda + lane_off;
    const unsigned short* gB0 = Bb + (long)rb0 * ldb + lane_off;
    const unsigned short* gB1 = Bb + (long)rb1 * ldb + lane_off;
    unsigned short* lA0 = As + ((w * 2 + 0) * 16) * 32;
    unsigned short* lA1 = As + ((w * 2 + 1) * 16) * 32;
    unsigned short* lB0 = Bs + ((w * 2 + 0) * 16) * 32;
    unsigned short* lB1 = Bs + ((w * 2 + 1) * 16) * 32;

#pragma unroll 1
    for (int k0 = 0; k0 < Kd; k0 += 32) {
        async_copy16(gA0 + k0, (void*)lA0);
        async_copy16(gA1 + k0, (void*)lA1);
        async_copy16(gB0 + k0, (void*)lB0);
        async_copy16(gB1 + k0, (void*)lB1);
        __syncthreads();
        half8 af[4], bfr[4];
#pragma unroll
        for (int ti = 0; ti < 4; ti++)
            af[ti] = *(const half8*)(As + (wr * 64 + ti * 16 + (l & 15)) * 32 + (l >> 4) * 8);
#pragma unroll
        for (int tj = 0; tj < 4; tj++)
            bfr[tj] = *(const half8*)(Bs + (wc * 64 + tj * 16 + (l & 15)) * 32 + (l >> 4) * 8);
#pragma unroll
        for (int ti = 0; ti < 4; ti++)
#pragma unroll
            for (int tj = 0; tj < 4; tj++)
                acc[ti][tj] = __builtin_amdgcn_mfma_f32_16x16x32_f16(
                    af[ti], bfr[tj], acc[ti][tj], 0, 0, 0);
        __syncthreads();
    }

    float* Cf = (float*)Cv + (long)z * cz;
    unsigned short* Ch = (unsigned short*)Cv + (long)z * cz;
    const float* bias_p = bias ? bias + (long)z * biasz : nullptr;
#pragma unroll
    for (int ti = 0; ti < 4; ti++) {
#pragma unroll
        for (int tj = 0; tj < 4; tj++) {
            const int c = col0 + wc * 64 + tj * 16 + (l & 15);
            const int rb = row0 + wr * 64 + ti * 16 + (l >> 4) * 4;
#pragma unroll
            for (int reg = 0; reg < 4; reg++) {
                int r = rb + reg;
                if (r >= M || c >= N) continue;
                float v = acc[ti][tj][reg] * scale;
                if (bias_p) v += bias_p[c];
                if (OF16) Ch[(long)r * ldc + c] = f2h(v);
                else      Cf[(long)r * ldc + c] = v;
            }
        }
    }
}

// ---------------------------------------------------------------------------
// GRAM kernel, fused-K: stage Ahi/Alo/Bhi/Blo ONCE per 32-k chunk (32 KB LDS),
// then 3 MFMA combos (hi.hi, hi.lo, lo.hi) per barrier — 48 MFMA/barrier and
// 2/3 the staging of the old 3-pass form. Triangular grid, 1/cdist epilogue
// + mirrored store (R7 epilogue). Combo regrouping shifts acc by ~ulp only.
// ---------------------------------------------------------------------------
__global__ __launch_bounds__(256)
void gram_kernel(const unsigned short* __restrict__ X,
                 float* __restrict__ C, const float* __restrict__ sqn, int nbm)
{
    __shared__ unsigned short Ah[128 * 32], Al[128 * 32];
    __shared__ unsigned short Bh[128 * 32], Bl[128 * 32];
    const int t = threadIdx.x;
    const int w = t >> 6, l = t & 63;
    const int wr = w >> 1, wc = w & 1;

    int tt = blockIdx.x, rem = nbm, bi = 0;
    while (tt >= rem) { tt -= rem; bi++; rem--; }
    const int bj = bi + tt;
    const int row0 = bi * 128, col0 = bj * 128;

    floatx4 acc[4][4];
#pragma unroll
    for (int i = 0; i < 4; i++)
#pragma unroll
        for (int j = 0; j < 4; j++) acc[i][j] = (floatx4){0.f, 0.f, 0.f, 0.f};

    int ra0 = row0 + (w * 2 + 0) * 16 + (l >> 2); ra0 = ra0 < N_PTS ? ra0 : N_PTS - 1;
    int ra1 = row0 + (w * 2 + 1) * 16 + (l >> 2); ra1 = ra1 < N_PTS ? ra1 : N_PTS - 1;
    int rb0 = col0 + (w * 2 + 0) * 16 + (l >> 2); rb0 = rb0 < N_PTS ? rb0 : N_PTS - 1;
    int rb1 = col0 + (w * 2 + 1) * 16 + (l >> 2); rb1 = rb1 < N_PTS ? rb1 : N_PTS - 1;
    const long lane_off = (l & 3) * 8;
    const unsigned short* gA0 = X + (long)ra0 * XSTR + lane_off;
    const unsigned short* gA1 = X + (long)ra1 * XSTR + lane_off;
    const unsigned short* gB0 = X + (long)rb0 * XSTR + lane_off;
    const unsigned short* gB1 = X + (long)rb1 * XSTR + lane_off;
    const long ldsoff0 = ((w * 2 + 0) * 16) * 32;
    const long ldsoff1 = ((w * 2 + 1) * 16) * 32;

#pragma unroll 1
    for (int k0 = 0; k0 < 1024; k0 += 32) {
        async_copy16(gA0 + k0, (void*)(Ah + ldsoff0));
        async_copy16(gA1 + k0, (void*)(Ah + ldsoff1));
        async_copy16(gA0 + k0 + 1024, (void*)(Al + ldsoff0));
        async_copy16(gA1 + k0 + 1024, (void*)(Al + ldsoff1));
        async_copy16(gB0 + k0, (void*)(Bh + ldsoff0));
        async_copy16(gB1 + k0, (void*)(Bh + ldsoff1));
        async_copy16(gB0 + k0 + 1024, (void*)(Bl + ldsoff0));
        async_copy16(gB1 + k0 + 1024, (void*)(Bl + ldsoff1));
        __syncthreads();

        const long aidx = (wr * 64 + (l & 15)) * 32 + (l >> 4) * 8;
        const long bidx = (wc * 64 + (l & 15)) * 32 + (l >> 4) * 8;
        half8 af[4], bfr[4];
        // combo 1: hi.hi
#pragma unroll
        for (int ti = 0; ti < 4; ti++) af[ti] = *(const half8*)(Ah + aidx + ti * 16 * 32);
#pragma unroll
        for (int tj = 0; tj < 4; tj++) bfr[tj] = *(const half8*)(Bh + bidx + tj * 16 * 32);
#pragma unroll
        for (int ti = 0; ti < 4; ti++)
#pragma unroll
            for (int tj = 0; tj < 4; tj++)
                acc[ti][tj] = __builtin_amdgcn_mfma_f32_16x16x32_f16(
                    af[ti], bfr[tj], acc[ti][tj], 0, 0, 0);
        // combo 2: hi.lo (af reused)
#pragma unroll
        for (int tj = 0; tj < 4; tj++) bfr[tj] = *(const half8*)(Bl + bidx + tj * 16 * 32);
#pragma unroll
        for (int ti = 0; ti < 4; ti++)
#pragma unroll
            for (int tj = 0; tj < 4; tj++)
                acc[ti][tj] = __builtin_amdgcn_mfma_f32_16x16x32_f16(
                    af[ti], bfr[tj], acc[ti][tj], 0, 0, 0);
        // combo 3: lo.hi
#pragma unroll
        for (int ti = 0; ti < 4; ti++) af[ti] = *(const half8*)(Al + aidx + ti * 16 * 32);
#pragma unroll
        for (int tj = 0; tj < 4; tj++) bfr[tj] = *(const half8*)(Bh + bidx + tj * 16 * 32);
#pragma unroll
        for (int ti = 0; ti < 4; ti++)
#pragma unroll
            for (int tj = 0; tj < 4; tj++)
                acc[ti][tj] = __builtin_amdgcn_mfma_f32_16x16x32_f16(
                    af[ti], bfr[tj], acc[ti][tj], 0, 0, 0);
        __syncthreads();
    }

#pragma unroll
    for (int ti = 0; ti < 4; ti++) {
#pragma unroll
        for (int tj = 0; tj < 4; tj++) {
            const int c = col0 + wc * 64 + tj * 16 + (l & 15);
            const int rb = row0 + wr * 64 + ti * 16 + (l >> 4) * 4;
            float rec4[4];
#pragma unroll
            for (int reg = 0; reg < 4; reg++) {
                int r = rb + reg;
                if (r >= N_PTS || c >= N_PTS) { rec4[reg] = 0.f; continue; }
                if (r == c) { rec4[reg] = INFINITY; }
                else {
                    float sq = sqn[r] + sqn[c] - 2.f * acc[ti][tj][reg];
                    rec4[reg] = 1.0f / sqrtf(fmaxf(sq, 0.f));
                }
                C[(long)r * N_PTS + c] = rec4[reg];
            }
            if (bi != bj && c < N_PTS && rb + 3 < N_PTS) {
                *(float4*)(C + (long)c * N_PTS + rb) =
                    make_float4(rec4[0], rec4[1], rec4[2], rec4[3]);
            }
        }
    }
}

// ---------------------------------------------------------------------------
// FAT KERNEL: block 0 = greedy FPS (frozen); blocks 1..96 = kk GEMM.
// ---------------------------------------------------------------------------
#define FPS_T 1024

__global__ __launch_bounds__(1024)
void fps_kk_kernel(const float* __restrict__ Drec, int* __restrict__ idxout,
                   const unsigned short* __restrict__ X,
                   const unsigned short* __restrict__ Wk_h,
                   const float* __restrict__ bk,
                   unsigned short* __restrict__ kk_h)
{
    __shared__ unsigned long long red[16];
    __shared__ int s_sel;
    __shared__ unsigned short As[4][128 * 32];
    __shared__ unsigned short Bs[128 * 32];
    const int t = threadIdx.x;

    if (blockIdx.x == 0) {
        const bool act = t < 750;
        float ds[8];
        if (act) {
            const float4* p = (const float4*)Drec + 2 * t;
            float4 a0 = p[0], a1 = p[1];
            ds[0] = a0.x; ds[1] = a0.y; ds[2] = a0.z; ds[3] = a0.w;
            ds[4] = a1.x; ds[5] = a1.y; ds[6] = a1.z; ds[7] = a1.w;
        } else {
#pragma unroll
            for (int j = 0; j < 8; j++) ds[j] = INFINITY;
        }
        if (t == 0) idxout[0] = 0;

        for (int it = 1; it < KSEL; it++) {
            float mv = ds[0]; int mi = 8 * t;
#pragma unroll
            for (int j = 1; j < 8; j++) {
                if (ds[j] < mv) { mv = ds[j]; mi = 8 * t + j; }
            }
            unsigned long long key = act
                ? (((unsigned long long)__float_as_uint(mv) << 32) | (unsigned)mi)
                : ~0ull;
#pragma unroll
            for (int o = 32; o > 0; o >>= 1) {
                unsigned long long other = __shfl_down(key, o);
                if (other < key) key = other;
            }
            if ((t & 63) == 0) red[t >> 6] = key;
            __syncthreads();
            if (t < 64) {
                unsigned long long k2 = (t < 16) ? red[t] : ~0ull;
#pragma unroll
                for (int o = 8; o > 0; o >>= 1) {
                    unsigned long long other = __shfl_down(k2, o);
                    if (other < k2) k2 = other;
                }
                if (t == 0) s_sel = (int)(unsigned)(k2 & 0xffffffffull);
            }
            __syncthreads();
            const int sel = s_sel;
            if (t == 0) idxout[it] = sel;
            if (act) {
                const float4* rp = (const float4*)(Drec + (long)sel * N_PTS) + 2 * t;
                float4 r0 = rp[0], r1 = rp[1];
                ds[0] += r0.x; ds[1] += r0.y; ds[2] += r0.z; ds[3] += r0.w;
                ds[4] += r1.x; ds[5] += r1.y; ds[6] += r1.z; ds[7] += r1.w;
            }
        }
        return;
    }

    // kk GEMM: 4 stacked 128x128 tiles per 1024-thread block
    const int b = blockIdx.x - 1;
    const int mg = b >> 3;
    const int nt = b & 7;
    const int w = t >> 6, l = t & 63;
    const int sub = w >> 2;
    const int wsu = w & 3;
    const int wr = wsu >> 1, wc = wsu & 1;
    const int row0 = (mg * 4 + sub) * 128;
    const int col0 = nt * 128;

    floatx4 acc[4][4];
#pragma unroll
    for (int i = 0; i < 4; i++)
#pragma unroll
        for (int j = 0; j < 4; j++) acc[i][j] = (floatx4){0.f, 0.f, 0.f, 0.f};

    int ra0 = row0 + (wsu * 2 + 0) * 16 + (l >> 2); ra0 = ra0 < N_PTS ? ra0 : N_PTS - 1;
    int ra1 = row0 + (wsu * 2 + 1) * 16 + (l >> 2); ra1 = ra1 < N_PTS ? ra1 : N_PTS - 1;
    const long lane_off = (l & 3) * 8;
    const unsigned short* gA0 = X + (long)ra0 * XSTR + lane_off;
    const unsigned short* gA1 = X + (long)ra1 * XSTR + lane_off;
    unsigned short* lA0 = As[sub] + ((wsu * 2 + 0) * 16) * 32;
    unsigned short* lA1 = As[sub] + ((wsu * 2 + 1) * 16) * 32;
    const int rb0 = col0 + (wsu * 2 + 0) * 16 + (l >> 2);
    const int rb1 = col0 + (wsu * 2 + 1) * 16 + (l >> 2);
    const unsigned short* gB0 = Wk_h + (long)rb0 * DIM + lane_off;
    const unsigned short* gB1 = Wk_h + (long)rb1 * DIM + lane_off;
    unsigned short* lB0 = Bs + ((wsu * 2 + 0) * 16) * 32;
    unsigned short* lB1 = Bs + ((wsu * 2 + 1) * 16) * 32;

#pragma unroll 1
    for (int k0 = 0; k0 < DIM; k0 += 32) {
        async_copy16(gA0 + k0, (void*)lA0);
        async_copy16(gA1 + k0, (void*)lA1);
        if (sub == 0) {
            async_copy16(gB0 + k0, (void*)lB0);
            async_copy16(gB1 + k0, (void*)lB1);
        }
        __syncthreads();
        half8 af[4], bfr[4];
#pragma unroll
        for (int ti = 0; ti < 4; ti++)
            af[ti] = *(const half8*)(As[sub] + (wr * 64 + ti * 16 + (l & 15)) * 32 + (l >> 4) * 8);
#pragma unroll
        for (int tj = 0; tj < 4; tj++)
            bfr[tj] = *(const half8*)(Bs + (wc * 64 + tj * 16 + (l & 15)) * 32 + (l >> 4) * 8);
#pragma unroll
        for (int ti = 0; ti < 4; ti++)
#pragma unroll
            for (int tj = 0; tj < 4; tj++)
                acc[ti][tj] = __builtin_amdgcn_mfma_f32_16x16x32_f16(
                    af[ti], bfr[tj], acc[ti][tj], 0, 0, 0);
        __syncthreads();
    }

#pragma unroll
    for (int ti = 0; ti < 4; ti++) {
#pragma unroll
        for (int tj = 0; tj < 4; tj++) {
            const int c = col0 + wc * 64 + tj * 16 + (l & 15);
            const int rbase = row0 + wr * 64 + ti * 16 + (l >> 4) * 4;
            const float bkc = bk[c];
#pragma unroll
            for (int reg = 0; reg < 4; reg++) {
                const int r = rbase + reg;
                if (r < N_PTS)
                    kk_h[(long)r * DIM + c] = f2h(acc[ti][tj][reg] + bkc);
            }
        }
    }
}

// ---------------------------------------------------------------------------
// fp32 SGEMM kept for the small Wv projection only.
// ---------------------------------------------------------------------------
#define BM 128
#define BN 128
#define BKK 8
#define TM 8
#define TN 8

template<bool TRANSB>
__global__ __launch_bounds__(256)
void sgemm_kernel(const float* __restrict__ A, long lda, long az,
                  const float* __restrict__ B, long ldb, long bz,
                  float* __restrict__ C, long ldc, long cz,
                  int M, int N, int Kd,
                  const float* __restrict__ bias, long biasz, float scale)
{
    __shared__ float As[BKK][BM];
    __shared__ float Bs[BKK][BN];
    const int t = threadIdx.x;
    const int z = blockIdx.z;
    A += (long)z * az; B += (long)z * bz; C += (long)z * cz;
    const float* bias_p = bias ? (bias + (long)z * biasz) : nullptr;
    const int row0 = blockIdx.y * BM;
    const int col0 = blockIdx.x * BN;
    const int tx = t & 15, ty = t >> 4;

    float acc[TM][TN];
#pragma unroll
    for (int i = 0; i < TM; i++)
#pragma unroll
        for (int j = 0; j < TN; j++) acc[i][j] = 0.f;

    const int lrow = t >> 1;
    const int lcol = (t & 1) * 4;

    for (int k0 = 0; k0 < Kd; k0 += BKK) {
        {
            int r = row0 + lrow; r = (r < M) ? r : (M - 1);
            float4 v = *(const float4*)(A + (long)r * lda + (k0 + lcol));
            As[lcol + 0][lrow] = v.x; As[lcol + 1][lrow] = v.y;
            As[lcol + 2][lrow] = v.z; As[lcol + 3][lrow] = v.w;
        }
        {
            int r = col0 + lrow; r = (r < N) ? r : (N - 1);
            float4 v = *(const float4*)(B + (long)r * ldb + (k0 + lcol));
            Bs[lcol + 0][lrow] = v.x; Bs[lcol + 1][lrow] = v.y;
            Bs[lcol + 2][lrow] = v.z; Bs[lcol + 3][lrow] = v.w;
        }
        __syncthreads();
#pragma unroll
        for (int kk = 0; kk < BKK; kk++) {
            float a[TM], b[TN];
#pragma unroll
            for (int i = 0; i < TM; i++) a[i] = As[kk][ty * TM + i];
#pragma unroll
            for (int j = 0; j < TN; j++) b[j] = Bs[kk][tx * TN + j];
#pragma unroll
            for (int i = 0; i < TM; i++)
#pragma unroll
                for (int j = 0; j < TN; j++)
                    acc[i][j] = fmaf(a[i], b[j], acc[i][j]);
        }
        __syncthreads();
    }
#pragma unroll
    for (int i = 0; i < TM; i++) {
        int r = row0 + ty * TM + i;
        if (r >= M) continue;
#pragma unroll
        for (int j = 0; j < TN; j++) {
            int c = col0 + tx * TN + j;
            if (c >= N) continue;
            float v = acc[i][j] * scale;
            if (bias_p) v += bias_p[c];
            C[(long)r * ldc + c] = v;
        }
    }
}

// ---------------------------------------------------------------------------
__global__ __launch_bounds__(256)
void sqnpack2_kernel(const float* __restrict__ feat,
                     unsigned short* __restrict__ X, float* __restrict__ sqn)
{
    const int r = blockIdx.x, t = threadIdx.x;
    float4 v = *(const float4*)(feat + (long)r * DIM + t * 4);
    float s = v.x * v.x + v.y * v.y + v.z * v.z + v.w * v.w;

    ushort4 hi, lo;
    hi.x = f2h(v.x); lo.x = f2h(v.x - h2f(hi.x));
    hi.y = f2h(v.y); lo.y = f2h(v.y - h2f(hi.y));
    hi.z = f2h(v.z); lo.z = f2h(v.z - h2f(hi.z));
    hi.w = f2h(v.w); lo.w = f2h(v.w - h2f(hi.w));
    *(ushort4*)(X + (long)r * XSTR + t * 4) = hi;
    *(ushort4*)(X + (long)r * XSTR + 1024 + t * 4) = lo;

#pragma unroll
    for (int o = 32; o > 0; o >>= 1) s += __shfl_down(s, o);
    __shared__ float sr[4];
    if ((t & 63) == 0) sr[t >> 6] = s;
    __syncthreads();
    if (t == 0) sqn[r] = sr[0] + sr[1] + sr[2] + sr[3];
}

__global__ __launch_bounds__(256)
void wconv2_kernel(const float* __restrict__ Wq, const float* __restrict__ Wk,
                   unsigned short* __restrict__ Wq_h, unsigned short* __restrict__ Wk_h)
{
    const int b = blockIdx.x;
    const float* src = (b < 1024) ? Wq : Wk;
    unsigned short* dst = (b < 1024) ? Wq_h : Wk_h;
    const long i = ((long)(b & 1023) * 256 + threadIdx.x) * 4;
    float4 v = *(const float4*)(src + i);
    ushort4 o;
    o.x = f2h(v.x); o.y = f2h(v.y); o.z = f2h(v.z); o.w = f2h(v.w);
    *(ushort4*)(dst + i) = o;
}

// featT[d][r] = f16(feat[r][d]), 1024 x 6016 (cols 6000..6015 zero)
__global__ __launch_bounds__(256)
void transpose_kernel(const float* __restrict__ feat, unsigned short* __restrict__ featT)
{
    __shared__ unsigned short tile[32][33];
    const int bx = blockIdx.x;
    const int by = blockIdx.y;
    const int t = threadIdx.x;
    const int lr = t >> 3;
    const int lc = (t & 7) * 4;
    const int r = by * 32 + lr;
    if (r < N_PTS) {
        float4 v = *(const float4*)(feat + (long)r * DIM + bx * 32 + lc);
        tile[lr][lc + 0] = f2h(v.x); tile[lr][lc + 1] = f2h(v.y);
        tile[lr][lc + 2] = f2h(v.z); tile[lr][lc + 3] = f2h(v.w);
    } else {
        tile[lr][lc + 0] = 0; tile[lr][lc + 1] = 0;
        tile[lr][lc + 2] = 0; tile[lr][lc + 3] = 0;
    }
    __syncthreads();
    const int orow = bx * 32 + lr;
    ushort4 o;
    o.x = tile[lc + 0][lr]; o.y = tile[lc + 1][lr];
    o.z = tile[lc + 2][lr]; o.w = tile[lc + 3][lr];
    *(ushort4*)(featT + (long)orow * WSTR + by * 32 + lc) = o;
}

__global__ __launch_bounds__(256)
void gatherb_kernel(const unsigned short* __restrict__ X, const int* __restrict__ idx,
                    unsigned short* __restrict__ roi)
{
    const int k = blockIdx.x, t = threadIdx.x;
    const unsigned short* src = X + (long)idx[k] * XSTR;   // hi part
    *(ushort4*)(roi + (long)k * DIM + t * 4) = *(const ushort4*)(src + t * 4);
}

// ---------------------------------------------------------------------------
// Gate + logit: one thread per (k,n); sin/cos once per (k,n). Coefficients
// in TRANSPOSED LDS layout swgT[e][g] read as float4 quads: 256 broadcast
// ds_read_b128 per thread instead of 1024 ds_read_b32 (R12 bottleneck above
// the ~94us FMA floor). FMA expression & g-order identical -> bit-identical.
// ---------------------------------------------------------------------------
__global__ __launch_bounds__(256)
void gatelogit_kernel(const float* __restrict__ bboxes,
                      const int* __restrict__ idx,
                      const float* __restrict__ Wg,
                      const float* __restrict__ bgp,
                      float* __restrict__ W)
{
    __shared__ float swgT[64][16];   // swgT[e][g] = Wg[g*64+e]
    __shared__ float sbg[GG];
    __shared__ float sbb[4];
    const int t = threadIdx.x;
    const int k = blockIdx.y;
    const int n = blockIdx.x * 256 + t;
    for (int i = t; i < GG * 64; i += 256) swgT[i & 63][i >> 6] = Wg[i];
    if (t < GG) sbg[t] = bgp[t];
    if (t < 4)  sbb[t] = bboxes[(long)idx[k] * 4 + t];
    __syncthreads();
    if (n >= N_PTS) return;

    const float x1 = sbb[0], y1 = sbb[1], x2 = sbb[2], y2 = sbb[3];
    const float w  = x2 - x1 + 1.f, h = y2 - y1 + 1.f;
    const float cx = 0.5f * (x1 + x2), cy = 0.5f * (y1 + y2);
    float4 rb = *(const float4*)(bboxes + (long)n * 4);
    const float wr = rb.z - rb.x + 1.f, hr = rb.w - rb.y + 1.f;
    const float cxr = 0.5f * (rb.x + rb.z), cyr = 0.5f * (rb.y + rb.w);

    float pos[4];
    pos[0] = __logf(fabsf((cx - cxr) / w) + 1e-3f);
    pos[1] = __logf(fabsf((cy - cyr) / h) + 1e-3f);
    pos[2] = __logf(w / wr);
    pos[3] = __logf(h / hr);

    const float rdm[8] = { 100.0f, 42.169650342858226f, 17.782794100389228f,
                           7.498942093324559f, 3.1622776601683795f,
                           1.333521432163324f, 0.5623413251903491f,
                           0.23713737056616552f };
    float aw[GG];
#pragma unroll
    for (int g = 0; g < GG; g++) aw[g] = sbg[g];
#pragma unroll
    for (int p = 0; p < 4; p++) {
#pragma unroll
        for (int f = 0; f < 8; f++) {
            const float arg = pos[p] * rdm[f];
            const float s_ = __sinf(arg), c_ = __cosf(arg);
            const int e = p * 16 + f;
            const float4* s4 = (const float4*)swgT[e];
            const float4* c4 = (const float4*)swgT[e + 8];
#pragma unroll
            for (int gq = 0; gq < 4; gq++) {
                const float4 sv = s4[gq], cv = c4[gq];
                aw[gq * 4 + 0] += sv.x * s_ + cv.x * c_;
                aw[gq * 4 + 1] += sv.y * s_ + cv.y * c_;
                aw[gq * 4 + 2] += sv.z * s_ + cv.z * c_;
                aw[gq * 4 + 3] += sv.w * s_ + cv.w * c_;
            }
        }
    }
    float* base = W + ((long)k * GG) * WSTR + n;
#pragma unroll
    for (int g = 0; g < GG; g++) {
        const float lg = __logf(fmaxf(aw[g], 0.f) + 1e-6f);
        base[(long)g * WSTR] += lg;
    }
}

// ---------------------------------------------------------------------------
// Softmax over n, one block per (k,g) row; in-place fp32 -> f16.
// ---------------------------------------------------------------------------
__global__ __launch_bounds__(256)
void softmax16_kernel(float* __restrict__ W)
{
    __shared__ float lg[WSTR];
    __shared__ float sred[4];
    __shared__ float sMS;
    const int t = threadIdx.x;
    float* rowp = W + (long)blockIdx.x * WSTR;

    float m = -INFINITY;
    for (int n = t; n < N_PTS; n += 256) {
        const float v = rowp[n];
        lg[n] = v;
        m = fmaxf(m, v);
    }
#pragma unroll
    for (int o = 32; o > 0; o >>= 1) m = fmaxf(m, __shfl_down(m, o));
    if ((t & 63) == 0) sred[t >> 6] = m;
    __syncthreads();
    if (t == 0) sMS = fmaxf(fmaxf(sred[0], sred[1]), fmaxf(sred[2], sred[3]));
    __syncthreads();
    m = sMS;
    __syncthreads();

    float s = 0.f;
    for (int n = t; n < N_PTS; n += 256) {
        const float e = __expf(lg[n] - m);
        lg[n] = e;
        s += e;
    }
#pragma unroll
    for (int o = 32; o > 0; o >>= 1) s += __shfl_down(s, o);
    if ((t & 63) == 0) sred[t >> 6] = s;
    __syncthreads();
    if (t == 0) sMS = sred[0] + sred[1] + sred[2] + sred[3];
    __syncthreads();
    const float inv = 1.0f / sMS;
    __syncthreads();

    unsigned short* orow = (unsigned short*)rowp;
    for (int n = t; n < WSTR; n += 256)
        orow[n] = (n < N_PTS) ? f2h(lg[n] * inv) : (unsigned short)0;
}

// out_t reduce: a += b (split-K partials), float4
__global__ __launch_bounds__(256)
void addbuf_kernel(float* __restrict__ a, const float* __restrict__ b)
{
    const long i = ((long)blockIdx.x * 256 + threadIdx.x) * 4;
    float4 va = *(const float4*)(a + i);
    float4 vb = *(const float4*)(b + i);
    va.x += vb.x; va.y += vb.y; va.z += vb.z; va.w += vb.w;
    *(float4*)(a + i) = va;
}

// ---------------------------------------------------------------------------
extern "C" void kernel_launch(void* const* d_in, const int* in_sizes, int n_in,
                              void* d_out, int out_size, void* d_ws, size_t ws_size,
                              hipStream_t stream)
{
    const float* feat   = (const float*)d_in[0];
    const float* bboxes = (const float*)d_in[1];
    const float* Wq     = (const float*)d_in[2];
    const float* bq     = (const float*)d_in[3];
    const float* Wk     = (const float*)d_in[4];
    const float* bk     = (const float*)d_in[5];
    const float* Wg     = (const float*)d_in[6];
    const float* bg     = (const float*)d_in[7];
    const float* Wv     = (const float*)d_in[8];
    const float* bv     = (const float*)d_in[9];
    float* out = (float*)d_out;
    float* ws  = (float*)d_ws;

    // ws layout (float offsets), peak ~186.7 MB (<= 190.72 MB known-safe):
    //  drec  [0, 36,000,000)   dead after FPS; then:
    //    W probs [0, 28,876,800)    fp32 logits -> f16 in place
    //    featT   [28,900,000, 31,980,192)   1024x6016 f16 (post-FPS)
    //    outt    [32,000,000, 36,915,200)   out_t partial z=0 (X dead by then)
    //    outt2   [37,000,000, 41,915,200)   out_t partial z=1
    //  X     [36,000,000, 42,144,000)  [hi|lo] f16; dead after gatherb
    //  kk_h  [42,200,000, 45,272,000)  f16 (written DURING fps, outside drec/X)
    //  q_h   [45,280,000, 45,433,600)
    //  roi_h [45,440,000, 45,593,600)
    //  Wq_h  [45,600,000, 46,124,288)
    //  Wk_h  [46,130,000, 46,654,288)
    //  sqn   [46,660,000, 46,666,000)
    //  idx   [46,666,000, ...)
    float* drec = ws;
    float* W    = ws;
    unsigned short* featT = (unsigned short*)(ws + 28900000);
    float* outt           = ws + 32000000;
    float* outt2          = ws + 37000000;
    unsigned short* X     = (unsigned short*)(ws + 36000000);
    unsigned short* kk_h  = (unsigned short*)(ws + 42200000);
    unsigned short* q_h   = (unsigned short*)(ws + 45280000);
    unsigned short* roi_h = (unsigned short*)(ws + 45440000);
    unsigned short* Wq_h  = (unsigned short*)(ws + 45600000);
    unsigned short* Wk_h  = (unsigned short*)(ws + 46130000);
    float* sqnbuf         = ws + 46660000;
    int*   idxbuf         = (int*)(ws + 46666000);
    if (ws_size < (size_t)186700000) return;

    sqnpack2_kernel<<<N_PTS, 256, 0, stream>>>(feat, X, sqnbuf);
    wconv2_kernel<<<2048, 256, 0, stream>>>(Wq, Wk, Wq_h, Wk_h);

    // Gram: fused-K (Ahi/Alo/Bhi/Blo staged once, 3 combos per barrier)
    gram_kernel<<<1128, 256, 0, stream>>>(X, drec, sqnbuf, 47);

    // FAT: block 0 = fps; blocks 1..96 = kk GEMM hidden in fps's shadow
    fps_kk_kernel<<<97, 1024, 0, stream>>>(drec, idxbuf, X, Wk_h, bk, kk_h);

    transpose_kernel<<<dim3(32, 188), 256, 0, stream>>>(feat, featT);
    gatherb_kernel<<<KSEL, 256, 0, stream>>>(X, idxbuf, roi_h);

    // q = roi @ Wq^T + bq  (f16 out)
    mfma_gemm<true><<<dim3(8, 3, 1), 256, 0, stream>>>(
        roi_h, 1024, 0, Wq_h, 1024, 0, q_h, 1024, 0,
        KSEL, DIM, DIM, bq, 0, 1.f);

    // aff = (q . kk^T)/8 per group -> W fp32  (batched z=16, K=64)
    mfma_gemm<false><<<dim3(47, 3, GG), 256, 0, stream>>>(
        q_h, 1024, 64, kk_h, 1024, 64, W, (long)GG * WSTR, WSTR,
        KSEL, N_PTS, 64, nullptr, 0, 0.125f);

    // gate + logit, then softmax (f16 probs in place)
    gatelogit_kernel<<<dim3(24, KSEL), 256, 0, stream>>>(
        bboxes, idxbuf, Wg, bg, W);
    softmax16_kernel<<<KSEL * GG, 256, 0, stream>>>(W);

    // out_t = P @ feat, split-K x2 via z (az=bz=3008), partials -> add
    mfma_gemm<false><<<dim3(8, 38, 2), 256, 0, stream>>>(
        (unsigned short*)W, 2 * WSTR, 3008, featT, WSTR, 3008,
        outt, DIM, 5000000,
        KSEL * GG, DIM, 3008, nullptr, 0, 1.f);
    addbuf_kernel<<<4800, 256, 0, stream>>>(outt, outt2);

    // out = out_t . Wv + bv (fp32, small)
    sgemm_kernel<true><<<dim3(1, 3, GG), 256, 0, stream>>>(
        outt, (long)GG * DIM, DIM, Wv, DIM, (long)DGR * DIM, out, DIM, DGR,
        KSEL, DGR, DIM, bv, DGR, 1.f);
}